// Round 1
// baseline (2063.430 us; speedup 1.0000x reference)
//
#include <hip/hip_runtime.h>

#define Bn 4096
#define Tn 100
#define Dn 64
#define Hn 128
#define ROWS 8   // batch rows per block (512 blocks -> 2 blocks/CU, 4 waves/SIMD)

typedef _Float16 half8v __attribute__((ext_vector_type(8)));
typedef _Float16 half4v __attribute__((ext_vector_type(4)));
typedef float    float4v __attribute__((ext_vector_type(4)));

// barrier: LDS-only drain (no vmcnt(0) -> x prefetch stays in flight)
#define BAR() asm volatile("s_waitcnt lgkmcnt(0)\ns_barrier" ::: "memory")

__device__ __forceinline__ float fast_tanh(float x) {
    float e = __expf(x + x);
    return 1.0f - 2.0f * __builtin_amdgcn_rcpf(e + 1.0f);
}
__device__ __forceinline__ float fast_sig(float x) {
    return __builtin_amdgcn_rcpf(1.0f + __expf(-x));
}
__device__ __forceinline__ float4v tanh4(float4v u) {
    float4v a;
#pragma unroll
    for (int r = 0; r < 4; r++) a[r] = fast_tanh(u[r]);
    return a;
}
__device__ __forceinline__ half4v pack4(float4v v) {
    half4v p;
#pragma unroll
    for (int r = 0; r < 4; r++) p[r] = (_Float16)v[r];
    return p;
}

// A-operand fragment of stationary weight W [n x ld]: lane gets W[n][k..k+7] fp32->fp16.
__device__ __forceinline__ half8v load_wfrag(const float* __restrict__ W, int ld, int n, int k) {
    const float* p = W + (size_t)n * ld + k;
    float4v a = *(const float4v*)p;
    float4v b = *(const float4v*)(p + 4);
    half8v r;
    r[0] = (_Float16)a[0]; r[1] = (_Float16)a[1]; r[2] = (_Float16)a[2]; r[3] = (_Float16)a[3];
    r[4] = (_Float16)b[0]; r[5] = (_Float16)b[1]; r[6] = (_Float16)b[2]; r[7] = (_Float16)b[3];
    return r;
}

// Persistent ODE-RNN kernel. 512 blocks x 512 threads (8 waves), 8 batch rows/block.
// 2 blocks/CU -> 4 waves/SIMD from two INDEPENDENT barrier groups: latency of the
// tanh->LDS->barrier->MFMA chain of one block hides under the other block's compute.
// Lanes m>=8 mirror lane m-8's LDS read addresses (broadcast, free) and their MFMA
// columns are discarded; all garbage values are tanh/GRU-bounded (finite, fp16-safe).
__global__ __launch_bounds__(512, 4) void odernn_kernel(
    const float* __restrict__ x_seq, const float* __restrict__ t_seq,
    const float* __restrict__ W1,   const float* __restrict__ b1,
    const float* __restrict__ W2,   const float* __restrict__ b2,
    const float* __restrict__ W_ih, const float* __restrict__ W_hh,
    const float* __restrict__ b_ih, const float* __restrict__ b_hh,
    const float* __restrict__ W_mu, const float* __restrict__ b_mu,
    const float* __restrict__ W_lv, const float* __restrict__ b_lv,
    float* __restrict__ out)
{
    __shared__ _Float16 vbuf[16 * 136];      // h exchange (fp16); rows 8..15 = dummy
    __shared__ _Float16 abuf[2][16 * 136];   // a_i / A / Abar exchange, ping-pong
    __shared__ _Float16 xbuf[ROWS * 72];     // x_t staging (8 rows)
    __shared__ float    ts_l[Tn];
    __shared__ float    c1s[Hn];             // c1 = b2 @ W1^T

    const int tid  = threadIdx.x;
    const int lane = tid & 63;
    const int w    = tid >> 6;        // wave 0..7 = n-tile owner
    const int q    = lane >> 4;
    const int m    = lane & 15;
    const int rowm = m & 7;           // valid-row mirror for reads (broadcast for m>=8)
    const int blk  = blockIdx.x;

    if (tid < Tn) ts_l[tid] = t_seq[tid];
    for (int i = tid; i < 16 * 136; i += 512) vbuf[i] = (_Float16)0.f;  // h0 = 0
    if (tid < Hn) {                                   // c1[n] = dot(b2, W1[n][:])
        float acc = 0.f;
        const float* r1 = W1 + (size_t)tid * Hn;
#pragma unroll 4
        for (int j = 0; j < Hn; j++) acc += b2[j] * r1[j];
        c1s[tid] = acc;
    }

    // ---- stationary weight fragments ----
    const int n0 = 16 * w + m;
    half8v w1f[4], w2f[4], whhf[3][4], wihf[3][2];
#pragma unroll
    for (int kt = 0; kt < 4; kt++) {
        w1f[kt] = load_wfrag(W1, Hn, n0, 32 * kt + q * 8);
        w2f[kt] = load_wfrag(W2, Hn, n0, 32 * kt + q * 8);
    }
#pragma unroll
    for (int g = 0; g < 3; g++) {                 // 0=r, 1=z, 2=n gate
        int n = 128 * g + n0;
#pragma unroll
        for (int kt = 0; kt < 4; kt++) whhf[g][kt] = load_wfrag(W_hh, Hn, n, 32 * kt + q * 8);
#pragma unroll
        for (int kt = 0; kt < 2; kt++) wihf[g][kt] = load_wfrag(W_ih, Dn, n, 32 * kt + q * 8);
    }
    float4v b1q = *(const float4v*)(b1 + 16 * w + q * 4);
    float4v b2q = *(const float4v*)(b2 + 16 * w + q * 4);
    float4v bihq[3], bhhq[3];
#pragma unroll
    for (int g = 0; g < 3; g++) {
        bihq[g] = *(const float4v*)(b_ih + 128 * g + 16 * w + q * 4);
        bhhq[g] = *(const float4v*)(b_hh + 128 * g + 16 * w + q * 4);
    }

    // ---- M = W1 @ W2 fragments (one-time VALU dot; A-layout: M[n0][32kt+8q+j]) ----
    float4v accM[4][2];
#pragma unroll
    for (int kt = 0; kt < 4; kt++) {
        float4v zz = {0.f, 0.f, 0.f, 0.f};
        accM[kt][0] = zz; accM[kt][1] = zz;
    }
    {
        const float* w1row = W1 + (size_t)n0 * Hn;
        for (int j = 0; j < Hn; j++) {
            float w1v = w1row[j];
            const float* w2r = W2 + (size_t)j * Hn + q * 8;
#pragma unroll
            for (int kt = 0; kt < 4; kt++) {
                float4v aa = *(const float4v*)(w2r + 32 * kt);
                float4v bb = *(const float4v*)(w2r + 32 * kt + 4);
#pragma unroll
                for (int r = 0; r < 4; r++) {
                    accM[kt][0][r] += w1v * aa[r];
                    accM[kt][1][r] += w1v * bb[r];
                }
            }
        }
    }
    half8v w21f[4];
#pragma unroll
    for (int kt = 0; kt < 4; kt++) {
#pragma unroll
        for (int r = 0; r < 4; r++) {
            w21f[kt][r]     = (_Float16)accM[kt][0][r];
            w21f[kt][r + 4] = (_Float16)accM[kt][1][r];
        }
    }

    float4v h = {0.f, 0.f, 0.f, 0.f};   // C-layout: n = 16w+4q+r, col m

    // x prefetch: 1 float/thread, wave w stages row w (8 rows x 64 cols)
    const int xrow = tid >> 6;          // == w
    const int xcol = tid & 63;
    const float* xptr = x_seq + (size_t)(blk * ROWS + xrow) * (Tn * Dn) + xcol;
    float xreg = *xptr;

    const int wslot = m * 136 + 16 * w + q * 4;     // C-layout store slot (full 16 rows)
    const int rslot = rowm * 136 + q * 8;           // B-frag read base (mirrored rows)

    // K=128 GEMM, 2 independent MFMA chains of 2 (shorter dep chain)
    auto gemm4 = [&](const half8v* Wf, const _Float16* base, float4v cin) -> float4v {
        const _Float16* p = base + rslot;
        half8v bf0 = *(const half8v*)(p);
        half8v bf1 = *(const half8v*)(p + 32);
        half8v bf2 = *(const half8v*)(p + 64);
        half8v bf3 = *(const half8v*)(p + 96);
        float4v o1 = cin;
        float4v o2 = {0.f, 0.f, 0.f, 0.f};
        o1 = __builtin_amdgcn_mfma_f32_16x16x32_f16(Wf[0], bf0, o1, 0, 0, 0);
        o2 = __builtin_amdgcn_mfma_f32_16x16x32_f16(Wf[2], bf2, o2, 0, 0, 0);
        o1 = __builtin_amdgcn_mfma_f32_16x16x32_f16(Wf[1], bf1, o1, 0, 0, 0);
        o2 = __builtin_amdgcn_mfma_f32_16x16x32_f16(Wf[3], bf3, o2, 0, 0, 0);
#pragma unroll
        for (int r = 0; r < 4; r++) o1[r] += o2[r];
        return o1;
    };

    float4v c1q;
    BAR();               // publish ts_l, c1s, vbuf(h0)
#pragma unroll
    for (int r = 0; r < 4; r++) c1q[r] = c1s[16 * w + q * 4 + r];
    const float4v zero4 = {0.f, 0.f, 0.f, 0.f};

#pragma unroll 1
    for (int t = 0; t < Tn; ++t) {
        // ---- stage x_t (wave w writes row w: 128B contiguous, conflict-free) ----
        xbuf[xrow * 72 + xcol] = (_Float16)xreg;
        float tc  = ts_l[t];
        float tp  = (t > 0) ? ts_l[t - 1] : tc;
        float sub = (tc - tp) * 0.25f;      // dt / N_RK4 (0 at t=0)
        float hs  = 0.5f * sub;
        float s6  = sub * (1.0f / 6.0f);
        BAR();                              // publish xbuf + vbuf(h)
        if (t + 1 < Tn) xreg = xptr[(t + 1) * Dn];

        // ---- interval A: gi = x Wih^T + bih  and  u_h = h W1^T + b1 ----
        float4v gi[3];
        {
            const _Float16* xp = xbuf + rowm * 72 + q * 8;
            half8v xf0 = *(const half8v*)(xp);
            half8v xf1 = *(const half8v*)(xp + 32);
#pragma unroll
            for (int g = 0; g < 3; g++) {
                float4v acc = bihq[g];
                acc = __builtin_amdgcn_mfma_f32_16x16x32_f16(wihf[g][0], xf0, acc, 0, 0, 0);
                acc = __builtin_amdgcn_mfma_f32_16x16x32_f16(wihf[g][1], xf1, acc, 0, 0, 0);
                gi[g] = acc;
            }
        }
        float4v u_h = gemm4(w1f, vbuf, b1q);

        if (sub != 0.0f) {
            float4v Abar = zero4;
#pragma unroll 1
            for (int s = 0; s < 4; s++) {
                float4v a1 = tanh4(u_h);
                float4v A  = a1;
                *(half4v*)(abuf[0] + wslot) = pack4(a1);
                BAR();
                float4v g = gemm4(w21f, abuf[0], c1q);      // a1 M^T + c1
                float4v u;
#pragma unroll
                for (int r = 0; r < 4; r++) u[r] = u_h[r] + hs * g[r];
                float4v a2 = tanh4(u);
#pragma unroll
                for (int r = 0; r < 4; r++) A[r] += 2.0f * a2[r];
                *(half4v*)(abuf[1] + wslot) = pack4(a2);
                BAR();
                g = gemm4(w21f, abuf[1], c1q);
#pragma unroll
                for (int r = 0; r < 4; r++) u[r] = u_h[r] + hs * g[r];
                float4v a3 = tanh4(u);
#pragma unroll
                for (int r = 0; r < 4; r++) A[r] += 2.0f * a3[r];
                *(half4v*)(abuf[0] + wslot) = pack4(a3);
                BAR();
                g = gemm4(w21f, abuf[0], c1q);
#pragma unroll
                for (int r = 0; r < 4; r++) u[r] = u_h[r] + sub * g[r];
                float4v a4 = tanh4(u);
#pragma unroll
                for (int r = 0; r < 4; r++) A[r] += a4[r];
                *(half4v*)(abuf[1] + wslot) = pack4(A);     // |A| <= 6, fp16 ok
                BAR();
                g = gemm4(w21f, abuf[1], zero4);            // A M^T
#pragma unroll
                for (int r = 0; r < 4; r++) {
                    u_h[r]  += s6 * g[r] + sub * c1q[r];
                    Abar[r] += A[r];
                }
            }
            // deferred h update: one W2-GEMM per step
            *(half4v*)(abuf[0] + wslot) = pack4(Abar);      // |Abar| <= 24, fp16 ok
            BAR();
            float4v gw = gemm4(w2f, abuf[0], zero4);
            float fourSub = 4.0f * sub;
#pragma unroll
            for (int r = 0; r < 4; r++) h[r] += s6 * gw[r] + fourSub * b2q[r];
            // publish post-RK h
            *(half4v*)(vbuf + wslot) = pack4(h);
            BAR();
        }
        // (sub==0: vbuf already holds h)

        // ---- gh = h Whh^T + bhh ----
        float4v gh[3];
        {
            const _Float16* p = vbuf + rslot;
            half8v bf0 = *(const half8v*)(p);
            half8v bf1 = *(const half8v*)(p + 32);
            half8v bf2 = *(const half8v*)(p + 64);
            half8v bf3 = *(const half8v*)(p + 96);
#pragma unroll
            for (int g = 0; g < 3; g++) {
                float4v acc = bhhq[g];
                acc = __builtin_amdgcn_mfma_f32_16x16x32_f16(whhf[g][0], bf0, acc, 0, 0, 0);
                acc = __builtin_amdgcn_mfma_f32_16x16x32_f16(whhf[g][1], bf1, acc, 0, 0, 0);
                acc = __builtin_amdgcn_mfma_f32_16x16x32_f16(whhf[g][2], bf2, acc, 0, 0, 0);
                acc = __builtin_amdgcn_mfma_f32_16x16x32_f16(whhf[g][3], bf3, acc, 0, 0, 0);
                gh[g] = acc;
            }
        }
        BAR();             // all waves done reading vbuf before GRU overwrite

        // ---- GRU (registers) ----
        {
            half4v pk;
#pragma unroll
            for (int r = 0; r < 4; r++) {
                float rr = fast_sig(gi[0][r] + gh[0][r]);
                float zz = fast_sig(gi[1][r] + gh[1][r]);
                float nn = fast_tanh(gi[2][r] + rr * gh[2][r]);
                float hv = (1.0f - zz) * nn + zz * h[r];
                h[r] = hv;
                pk[r] = (_Float16)hv;
            }
            *(half4v*)(vbuf + wslot) = pk;
        }
        // loop-top barrier publishes vbuf
    }

    BAR();

    // ---- epilogue: mu / logvar (store only valid rows m<8) ----
#pragma unroll
    for (int mat = 0; mat < 2; mat++) {
        const float* Wm = mat ? W_lv : W_mu;
        const float* bm = mat ? b_lv : b_mu;
        float4v acc = *(const float4v*)(bm + 16 * w + q * 4);
        const _Float16* p = vbuf + rslot;
#pragma unroll
        for (int kt = 0; kt < 4; kt++) {
            half8v af = load_wfrag(Wm, Hn, n0, 32 * kt + q * 8);
            acc = __builtin_amdgcn_mfma_f32_16x16x32_f16(af, *(const half8v*)(p + kt * 32), acc, 0, 0, 0);
        }
        if (m < ROWS) {
            *(float4v*)(out + (size_t)mat * Bn * Hn + (size_t)(blk * ROWS + m) * Hn + 16 * w + q * 4) = acc;
        }
    }
}

extern "C" void kernel_launch(void* const* d_in, const int* in_sizes, int n_in,
                              void* d_out, int out_size, void* d_ws, size_t ws_size,
                              hipStream_t stream) {
    (void)in_sizes; (void)n_in; (void)d_ws; (void)ws_size; (void)out_size;
    odernn_kernel<<<dim3(Bn / ROWS), dim3(512), 0, stream>>>(
        (const float*)d_in[0],  (const float*)d_in[1],  (const float*)d_in[2],
        (const float*)d_in[3],  (const float*)d_in[4],  (const float*)d_in[5],
        (const float*)d_in[6],  (const float*)d_in[7],  (const float*)d_in[8],
        (const float*)d_in[9],  (const float*)d_in[10], (const float*)d_in[11],
        (const float*)d_in[12], (const float*)d_in[13], (float*)d_out);
}

// Round 2
// 1473.469 us; speedup vs baseline: 1.4004x; 1.4004x over previous
//
#include <hip/hip_runtime.h>

#define Bn 4096
#define Tn 100
#define Dn 64
#define Hn 128
#define ROWS 8   // batch rows per block (512 blocks -> 2 blocks/CU, 4 waves/SIMD)

typedef _Float16 half8v __attribute__((ext_vector_type(8)));
typedef _Float16 half4v __attribute__((ext_vector_type(4)));
typedef float    float4v __attribute__((ext_vector_type(4)));

// barrier: LDS-only drain (no vmcnt(0) -> x prefetch stays in flight)
#define BAR() asm volatile("s_waitcnt lgkmcnt(0)\ns_barrier" ::: "memory")

__device__ __forceinline__ float fast_tanh(float x) {
    float e = __expf(x + x);
    return 1.0f - 2.0f * __builtin_amdgcn_rcpf(e + 1.0f);
}
__device__ __forceinline__ float fast_sig(float x) {
    return __builtin_amdgcn_rcpf(1.0f + __expf(-x));
}
__device__ __forceinline__ float4v tanh4(float4v u) {
    float4v a;
#pragma unroll
    for (int r = 0; r < 4; r++) a[r] = fast_tanh(u[r]);
    return a;
}
__device__ __forceinline__ half4v pack4(float4v v) {
    half4v p;
#pragma unroll
    for (int r = 0; r < 4; r++) p[r] = (_Float16)v[r];
    return p;
}

// A-operand fragment of stationary weight W [n x ld]: lane gets W[n][k..k+7] fp32->fp16.
__device__ __forceinline__ half8v load_wfrag(const float* __restrict__ W, int ld, int n, int k) {
    const float* p = W + (size_t)n * ld + k;
    float4v a = *(const float4v*)p;
    float4v b = *(const float4v*)(p + 4);
    half8v r;
    r[0] = (_Float16)a[0]; r[1] = (_Float16)a[1]; r[2] = (_Float16)a[2]; r[3] = (_Float16)a[3];
    r[4] = (_Float16)b[0]; r[5] = (_Float16)b[1]; r[6] = (_Float16)b[2]; r[7] = (_Float16)b[3];
    return r;
}

// Persistent ODE-RNN kernel. 512 blocks x 512 threads (8 waves), 8 batch rows/block.
// 2 blocks/CU -> 4 waves/SIMD from two INDEPENDENT barrier groups: latency of the
// tanh->LDS->barrier->MFMA chain of one block hides under the other block's compute.
// NOTE: plain __launch_bounds__(512) — the (512,4) min-waves variant forced a
// 64-arch-VGPR budget and spilled all weight fragments (5.4 GB scratch traffic).
// Lanes m>=8 mirror lane m-8's LDS read addresses (broadcast, free) and their MFMA
// columns are discarded; all garbage values are tanh/GRU-bounded (finite, fp16-safe).
__global__ __launch_bounds__(512) void odernn_kernel(
    const float* __restrict__ x_seq, const float* __restrict__ t_seq,
    const float* __restrict__ W1,   const float* __restrict__ b1,
    const float* __restrict__ W2,   const float* __restrict__ b2,
    const float* __restrict__ W_ih, const float* __restrict__ W_hh,
    const float* __restrict__ b_ih, const float* __restrict__ b_hh,
    const float* __restrict__ W_mu, const float* __restrict__ b_mu,
    const float* __restrict__ W_lv, const float* __restrict__ b_lv,
    float* __restrict__ out)
{
    __shared__ _Float16 vbuf[16 * 136];      // h exchange (fp16); rows 8..15 = dummy
    __shared__ _Float16 abuf[2][16 * 136];   // a_i / A / Abar exchange, ping-pong
    __shared__ _Float16 xbuf[ROWS * 72];     // x_t staging (8 rows)
    __shared__ float    ts_l[Tn];
    __shared__ float    c1s[Hn];             // c1 = b2 @ W1^T

    const int tid  = threadIdx.x;
    const int lane = tid & 63;
    const int w    = tid >> 6;        // wave 0..7 = n-tile owner
    const int q    = lane >> 4;
    const int m    = lane & 15;
    const int rowm = m & 7;           // valid-row mirror for reads (broadcast for m>=8)
    const int blk  = blockIdx.x;

    if (tid < Tn) ts_l[tid] = t_seq[tid];
    for (int i = tid; i < 16 * 136; i += 512) vbuf[i] = (_Float16)0.f;  // h0 = 0
    if (tid < Hn) {                                   // c1[n] = dot(b2, W1[n][:])
        float acc = 0.f;
        const float* r1 = W1 + (size_t)tid * Hn;
#pragma unroll 4
        for (int j = 0; j < Hn; j++) acc += b2[j] * r1[j];
        c1s[tid] = acc;
    }

    // ---- stationary weight fragments ----
    const int n0 = 16 * w + m;
    half8v w1f[4], w2f[4], whhf[3][4], wihf[3][2];
#pragma unroll
    for (int kt = 0; kt < 4; kt++) {
        w1f[kt] = load_wfrag(W1, Hn, n0, 32 * kt + q * 8);
        w2f[kt] = load_wfrag(W2, Hn, n0, 32 * kt + q * 8);
    }
#pragma unroll
    for (int g = 0; g < 3; g++) {                 // 0=r, 1=z, 2=n gate
        int n = 128 * g + n0;
#pragma unroll
        for (int kt = 0; kt < 4; kt++) whhf[g][kt] = load_wfrag(W_hh, Hn, n, 32 * kt + q * 8);
#pragma unroll
        for (int kt = 0; kt < 2; kt++) wihf[g][kt] = load_wfrag(W_ih, Dn, n, 32 * kt + q * 8);
    }
    float4v b1q = *(const float4v*)(b1 + 16 * w + q * 4);
    float4v b2q = *(const float4v*)(b2 + 16 * w + q * 4);
    // bias folding: r,z gates always consume gi+gh summed -> fold b_hh[g] into the
    // gi C-in for g=0,1 (saves 8 live VGPRs); only the n-gate keeps separate biases.
    float4v bi0, bi1, bin, bhn;
    {
        float4v a, b;
        a = *(const float4v*)(b_ih + 0   + 16 * w + q * 4);
        b = *(const float4v*)(b_hh + 0   + 16 * w + q * 4);
#pragma unroll
        for (int r = 0; r < 4; r++) bi0[r] = a[r] + b[r];
        a = *(const float4v*)(b_ih + 128 + 16 * w + q * 4);
        b = *(const float4v*)(b_hh + 128 + 16 * w + q * 4);
#pragma unroll
        for (int r = 0; r < 4; r++) bi1[r] = a[r] + b[r];
        bin = *(const float4v*)(b_ih + 256 + 16 * w + q * 4);
        bhn = *(const float4v*)(b_hh + 256 + 16 * w + q * 4);
    }

    // ---- M = W1 @ W2 fragments (one-time VALU dot; A-layout: M[n0][32kt+8q+j]) ----
    float4v accM[4][2];
#pragma unroll
    for (int kt = 0; kt < 4; kt++) {
        float4v zz = {0.f, 0.f, 0.f, 0.f};
        accM[kt][0] = zz; accM[kt][1] = zz;
    }
    {
        const float* w1row = W1 + (size_t)n0 * Hn;
        for (int j = 0; j < Hn; j++) {
            float w1v = w1row[j];
            const float* w2r = W2 + (size_t)j * Hn + q * 8;
#pragma unroll
            for (int kt = 0; kt < 4; kt++) {
                float4v aa = *(const float4v*)(w2r + 32 * kt);
                float4v bb = *(const float4v*)(w2r + 32 * kt + 4);
#pragma unroll
                for (int r = 0; r < 4; r++) {
                    accM[kt][0][r] += w1v * aa[r];
                    accM[kt][1][r] += w1v * bb[r];
                }
            }
        }
    }
    half8v w21f[4];
#pragma unroll
    for (int kt = 0; kt < 4; kt++) {
#pragma unroll
        for (int r = 0; r < 4; r++) {
            w21f[kt][r]     = (_Float16)accM[kt][0][r];
            w21f[kt][r + 4] = (_Float16)accM[kt][1][r];
        }
    }

    float4v h = {0.f, 0.f, 0.f, 0.f};   // C-layout: n = 16w+4q+r, col m

    // x prefetch: 1 float/thread, wave w stages row w (8 rows x 64 cols)
    const int xrow = tid >> 6;          // == w
    const int xcol = tid & 63;
    const float* xptr = x_seq + (size_t)(blk * ROWS + xrow) * (Tn * Dn) + xcol;
    float xreg = *xptr;

    const int wslot = m * 136 + 16 * w + q * 4;     // C-layout store slot (full 16 rows)
    const int rslot = rowm * 136 + q * 8;           // B-frag read base (mirrored rows)

    // K=128 GEMM, 2 independent MFMA chains of 2 (shorter dep chain)
    auto gemm4 = [&](const half8v* Wf, const _Float16* base, float4v cin) -> float4v {
        const _Float16* p = base + rslot;
        half8v bf0 = *(const half8v*)(p);
        half8v bf1 = *(const half8v*)(p + 32);
        half8v bf2 = *(const half8v*)(p + 64);
        half8v bf3 = *(const half8v*)(p + 96);
        float4v o1 = cin;
        float4v o2 = {0.f, 0.f, 0.f, 0.f};
        o1 = __builtin_amdgcn_mfma_f32_16x16x32_f16(Wf[0], bf0, o1, 0, 0, 0);
        o2 = __builtin_amdgcn_mfma_f32_16x16x32_f16(Wf[2], bf2, o2, 0, 0, 0);
        o1 = __builtin_amdgcn_mfma_f32_16x16x32_f16(Wf[1], bf1, o1, 0, 0, 0);
        o2 = __builtin_amdgcn_mfma_f32_16x16x32_f16(Wf[3], bf3, o2, 0, 0, 0);
#pragma unroll
        for (int r = 0; r < 4; r++) o1[r] += o2[r];
        return o1;
    };

    float4v c1q;
    BAR();               // publish ts_l, c1s, vbuf(h0)
#pragma unroll
    for (int r = 0; r < 4; r++) c1q[r] = c1s[16 * w + q * 4 + r];
    const float4v zero4 = {0.f, 0.f, 0.f, 0.f};

#pragma unroll 1
    for (int t = 0; t < Tn; ++t) {
        // ---- stage x_t (wave w writes row w: 128B contiguous, conflict-free) ----
        xbuf[xrow * 72 + xcol] = (_Float16)xreg;
        float tc  = ts_l[t];
        float tp  = (t > 0) ? ts_l[t - 1] : tc;
        float sub = (tc - tp) * 0.25f;      // dt / N_RK4 (0 at t=0)
        float hs  = 0.5f * sub;
        float s6  = sub * (1.0f / 6.0f);
        BAR();                              // publish xbuf + vbuf(h)
        if (t + 1 < Tn) xreg = xptr[(t + 1) * Dn];

        // ---- interval A: gi = x Wih^T + biases  and  u_h = h W1^T + b1 ----
        float4v gi[3];
        {
            const _Float16* xp = xbuf + rowm * 72 + q * 8;
            half8v xf0 = *(const half8v*)(xp);
            half8v xf1 = *(const half8v*)(xp + 32);
#pragma unroll
            for (int g = 0; g < 3; g++) {
                float4v acc = (g == 0) ? bi0 : (g == 1) ? bi1 : bin;
                acc = __builtin_amdgcn_mfma_f32_16x16x32_f16(wihf[g][0], xf0, acc, 0, 0, 0);
                acc = __builtin_amdgcn_mfma_f32_16x16x32_f16(wihf[g][1], xf1, acc, 0, 0, 0);
                gi[g] = acc;
            }
        }
        float4v u_h = gemm4(w1f, vbuf, b1q);

        if (sub != 0.0f) {
            float4v Abar = zero4;
#pragma unroll 1
            for (int s = 0; s < 4; s++) {
                float4v a1 = tanh4(u_h);
                float4v A  = a1;
                *(half4v*)(abuf[0] + wslot) = pack4(a1);
                BAR();
                float4v g = gemm4(w21f, abuf[0], c1q);      // a1 M^T + c1
                float4v u;
#pragma unroll
                for (int r = 0; r < 4; r++) u[r] = u_h[r] + hs * g[r];
                float4v a2 = tanh4(u);
#pragma unroll
                for (int r = 0; r < 4; r++) A[r] += 2.0f * a2[r];
                *(half4v*)(abuf[1] + wslot) = pack4(a2);
                BAR();
                g = gemm4(w21f, abuf[1], c1q);
#pragma unroll
                for (int r = 0; r < 4; r++) u[r] = u_h[r] + hs * g[r];
                float4v a3 = tanh4(u);
#pragma unroll
                for (int r = 0; r < 4; r++) A[r] += 2.0f * a3[r];
                *(half4v*)(abuf[0] + wslot) = pack4(a3);
                BAR();
                g = gemm4(w21f, abuf[0], c1q);
#pragma unroll
                for (int r = 0; r < 4; r++) u[r] = u_h[r] + sub * g[r];
                float4v a4 = tanh4(u);
#pragma unroll
                for (int r = 0; r < 4; r++) A[r] += a4[r];
                *(half4v*)(abuf[1] + wslot) = pack4(A);     // |A| <= 6, fp16 ok
                BAR();
                g = gemm4(w21f, abuf[1], zero4);            // A M^T
#pragma unroll
                for (int r = 0; r < 4; r++) {
                    u_h[r]  += s6 * g[r] + sub * c1q[r];
                    Abar[r] += A[r];
                }
            }
            // deferred h update: one W2-GEMM per step
            *(half4v*)(abuf[0] + wslot) = pack4(Abar);      // |Abar| <= 24, fp16 ok
            BAR();
            float4v gw = gemm4(w2f, abuf[0], zero4);
            float fourSub = 4.0f * sub;
#pragma unroll
            for (int r = 0; r < 4; r++) h[r] += s6 * gw[r] + fourSub * b2q[r];
            // publish post-RK h
            *(half4v*)(vbuf + wslot) = pack4(h);
            BAR();
        }
        // (sub==0: vbuf already holds h)

        // ---- gh = h Whh^T (+bhn for n-gate only; r,z biases folded into gi) ----
        float4v gh[3];
        {
            const _Float16* p = vbuf + rslot;
            half8v bf0 = *(const half8v*)(p);
            half8v bf1 = *(const half8v*)(p + 32);
            half8v bf2 = *(const half8v*)(p + 64);
            half8v bf3 = *(const half8v*)(p + 96);
#pragma unroll
            for (int g = 0; g < 3; g++) {
                float4v acc = (g == 2) ? bhn : zero4;
                acc = __builtin_amdgcn_mfma_f32_16x16x32_f16(whhf[g][0], bf0, acc, 0, 0, 0);
                acc = __builtin_amdgcn_mfma_f32_16x16x32_f16(whhf[g][1], bf1, acc, 0, 0, 0);
                acc = __builtin_amdgcn_mfma_f32_16x16x32_f16(whhf[g][2], bf2, acc, 0, 0, 0);
                acc = __builtin_amdgcn_mfma_f32_16x16x32_f16(whhf[g][3], bf3, acc, 0, 0, 0);
                gh[g] = acc;
            }
        }
        BAR();             // all waves done reading vbuf before GRU overwrite

        // ---- GRU (registers) ----
        {
            half4v pk;
#pragma unroll
            for (int r = 0; r < 4; r++) {
                float rr = fast_sig(gi[0][r] + gh[0][r]);
                float zz = fast_sig(gi[1][r] + gh[1][r]);
                float nn = fast_tanh(gi[2][r] + rr * gh[2][r]);
                float hv = (1.0f - zz) * nn + zz * h[r];
                h[r] = hv;
                pk[r] = (_Float16)hv;
            }
            *(half4v*)(vbuf + wslot) = pk;
        }
        // loop-top barrier publishes vbuf
    }

    BAR();

    // ---- epilogue: mu / logvar (store only valid rows m<8) ----
#pragma unroll
    for (int mat = 0; mat < 2; mat++) {
        const float* Wm = mat ? W_lv : W_mu;
        const float* bm = mat ? b_lv : b_mu;
        float4v acc = *(const float4v*)(bm + 16 * w + q * 4);
        const _Float16* p = vbuf + rslot;
#pragma unroll
        for (int kt = 0; kt < 4; kt++) {
            half8v af = load_wfrag(Wm, Hn, n0, 32 * kt + q * 8);
            acc = __builtin_amdgcn_mfma_f32_16x16x32_f16(af, *(const half8v*)(p + kt * 32), acc, 0, 0, 0);
        }
        if (m < ROWS) {
            *(float4v*)(out + (size_t)mat * Bn * Hn + (size_t)(blk * ROWS + m) * Hn + 16 * w + q * 4) = acc;
        }
    }
}

extern "C" void kernel_launch(void* const* d_in, const int* in_sizes, int n_in,
                              void* d_out, int out_size, void* d_ws, size_t ws_size,
                              hipStream_t stream) {
    (void)in_sizes; (void)n_in; (void)d_ws; (void)ws_size; (void)out_size;
    odernn_kernel<<<dim3(Bn / ROWS), dim3(512), 0, stream>>>(
        (const float*)d_in[0],  (const float*)d_in[1],  (const float*)d_in[2],
        (const float*)d_in[3],  (const float*)d_in[4],  (const float*)d_in[5],
        (const float*)d_in[6],  (const float*)d_in[7],  (const float*)d_in[8],
        (const float*)d_in[9],  (const float*)d_in[10], (const float*)d_in[11],
        (const float*)d_in[12], (const float*)d_in[13], (float*)d_out);
}

// Round 4
// 921.461 us; speedup vs baseline: 2.2393x; 1.5991x over previous
//
#include <hip/hip_runtime.h>

#define Bn 4096
#define Tn 100
#define Dn 64
#define Hn 128

typedef _Float16 half8v __attribute__((ext_vector_type(8)));
typedef _Float16 half4v __attribute__((ext_vector_type(4)));
typedef float    float4v __attribute__((ext_vector_type(4)));

// barrier: LDS-only drain (no vmcnt(0) -> x prefetch stays in flight)
#define BAR() asm volatile("s_waitcnt lgkmcnt(0)\ns_barrier" ::: "memory")

__device__ __forceinline__ float fast_tanh(float x) {
    float e = __expf(x + x);
    return 1.0f - 2.0f * __builtin_amdgcn_rcpf(e + 1.0f);
}
__device__ __forceinline__ float fast_sig(float x) {
    return __builtin_amdgcn_rcpf(1.0f + __expf(-x));
}
__device__ __forceinline__ float4v tanh4(float4v u) {
    float4v a;
#pragma unroll
    for (int r = 0; r < 4; r++) a[r] = fast_tanh(u[r]);
    return a;
}
__device__ __forceinline__ half4v pack4(float4v v) {
    half4v p;
#pragma unroll
    for (int r = 0; r < 4; r++) p[r] = (_Float16)v[r];
    return p;
}

// A-operand fragment of stationary weight W [n x ld] from GLOBAL fp32.
__device__ __forceinline__ half8v load_wfrag(const float* __restrict__ W, int ld, int n, int k) {
    const float* p = W + (size_t)n * ld + k;
    float4v a = *(const float4v*)p;
    float4v b = *(const float4v*)(p + 4);
    half8v r;
    r[0] = (_Float16)a[0]; r[1] = (_Float16)a[1]; r[2] = (_Float16)a[2]; r[3] = (_Float16)a[3];
    r[4] = (_Float16)b[0]; r[5] = (_Float16)b[1]; r[6] = (_Float16)b[2]; r[7] = (_Float16)b[3];
    return r;
}

struct Bfrag { half8v b0, b1, b2, b3; };

// Persistent ODE-RNN kernel. 256 blocks x 256 threads (4 waves, 1 wave/SIMD).
// Each wave owns 32 n-outputs (2 MFMA n-tiles); all 16 batch rows real.
// One wave per SIMD: the serial tanh->LDS->bar->MFMA chain runs at full issue
// rate; barrier spans 4 waves on 4 SIMDs; activation-tile LDS read duplication
// drops 8x -> 4x (both n-tiles of a wave share one B-frag read).
// Hot weights (M, Whh, Wih) register-resident; once-per-step W1/W2 staged in
// LDS as fp16 rows (A-frag readable). LDS total ~86 KB, 1 block/CU.
// __launch_bounds__(256,1): 1 wave/EU -> full 512-VGPR budget (NO spill; the
// (512,4) variant in round 1 proved a tight bound spills all fragments).
__global__ __launch_bounds__(256, 1) void odernn_kernel(
    const float* __restrict__ x_seq, const float* __restrict__ t_seq,
    const float* __restrict__ W1,   const float* __restrict__ b1,
    const float* __restrict__ W2,   const float* __restrict__ b2,
    const float* __restrict__ W_ih, const float* __restrict__ W_hh,
    const float* __restrict__ b_ih, const float* __restrict__ b_hh,
    const float* __restrict__ W_mu, const float* __restrict__ b_mu,
    const float* __restrict__ W_lv, const float* __restrict__ b_lv,
    float* __restrict__ out)
{
    __shared__ _Float16 w1s[128 * 136];      // W1 rows, fp16 (A-frag source)
    __shared__ _Float16 w2s[128 * 136];      // W2 rows, fp16
    __shared__ _Float16 vbuf[16 * 136];      // h exchange (fp16, [m][n])
    __shared__ _Float16 abuf[2][16 * 136];   // a_i / A / Abar exchange, ping-pong
    __shared__ _Float16 xbuf[16 * 72];       // x_t staging
    __shared__ float    ts_l[Tn];
    __shared__ float    c1s[Hn];             // c1 = b2 @ W1^T

    const int tid  = threadIdx.x;
    const int lane = tid & 63;
    const int w    = tid >> 6;        // wave 0..3: owns n in [32w, 32w+32)
    const int q    = lane >> 4;
    const int m    = lane & 15;       // batch row (all 16 real)
    const int blk  = blockIdx.x;

    // ---- one-time staging ----
    for (int i = tid; i < 128 * 128; i += 256) {
        int r = i >> 7, c = i & 127;
        w1s[r * 136 + c] = (_Float16)W1[i];
        w2s[r * 136 + c] = (_Float16)W2[i];
    }
    if (tid < Tn) ts_l[tid] = t_seq[tid];
    for (int i = tid; i < 16 * 136; i += 256) vbuf[i] = (_Float16)0.f;  // h0 = 0
    if (tid < Hn) {                                   // c1[n] = dot(b2, W1[n][:])
        float acc = 0.f;
        const float* r1 = W1 + (size_t)tid * Hn;
#pragma unroll 4
        for (int j = 0; j < Hn; j++) acc += b2[j] * r1[j];
        c1s[tid] = acc;
    }

    // ---- M = W1 @ W2 fragments (fp32 one-time dot), 2 n-tiles per wave ----
    // Full unroll: compile-time tt keeps w21f in registers (runtime-indexed
    // ext_vector arrays get demoted to scratch).
    half8v w21f[2][4];
#pragma unroll
    for (int tt = 0; tt < 2; tt++) {
        int n0t = 32 * w + 16 * tt + m;
        float4v accM[4][2];
#pragma unroll
        for (int kt = 0; kt < 4; kt++) {
            float4v zz = {0.f, 0.f, 0.f, 0.f};
            accM[kt][0] = zz; accM[kt][1] = zz;
        }
        const float* w1row = W1 + (size_t)n0t * Hn;
        for (int j = 0; j < Hn; j++) {
            float w1v = w1row[j];
            const float* w2r = W2 + (size_t)j * Hn + q * 8;
#pragma unroll
            for (int kt = 0; kt < 4; kt++) {
                float4v aa = *(const float4v*)(w2r + 32 * kt);
                float4v bb = *(const float4v*)(w2r + 32 * kt + 4);
#pragma unroll
                for (int r = 0; r < 4; r++) {
                    accM[kt][0][r] += w1v * aa[r];
                    accM[kt][1][r] += w1v * bb[r];
                }
            }
        }
#pragma unroll
        for (int kt = 0; kt < 4; kt++) {
#pragma unroll
            for (int r = 0; r < 4; r++) {
                w21f[tt][kt][r]     = (_Float16)accM[kt][0][r];
                w21f[tt][kt][r + 4] = (_Float16)accM[kt][1][r];
            }
        }
    }

    // ---- register-resident GRU weights (2 tiles per wave) ----
    half8v whhf[3][2][4], wihf[3][2][2];
#pragma unroll
    for (int g = 0; g < 3; g++) {
#pragma unroll
        for (int tt = 0; tt < 2; tt++) {
            int n = 128 * g + 32 * w + 16 * tt + m;
#pragma unroll
            for (int kt = 0; kt < 4; kt++) whhf[g][tt][kt] = load_wfrag(W_hh, Hn, n, 32 * kt + q * 8);
#pragma unroll
            for (int kt = 0; kt < 2; kt++) wihf[g][tt][kt] = load_wfrag(W_ih, Dn, n, 32 * kt + q * 8);
        }
    }
    // biases per tile (r,z gate b_hh folded into gi C-in)
    float4v b1q[2], b2q[2], bi0[2], bi1[2], bin[2], bhn[2];
#pragma unroll
    for (int tt = 0; tt < 2; tt++) {
        int nb = 32 * w + 16 * tt + 4 * q;
        b1q[tt] = *(const float4v*)(b1 + nb);
        b2q[tt] = *(const float4v*)(b2 + nb);
        float4v a, b;
        a = *(const float4v*)(b_ih + 0   + nb);
        b = *(const float4v*)(b_hh + 0   + nb);
#pragma unroll
        for (int r = 0; r < 4; r++) bi0[tt][r] = a[r] + b[r];
        a = *(const float4v*)(b_ih + 128 + nb);
        b = *(const float4v*)(b_hh + 128 + nb);
#pragma unroll
        for (int r = 0; r < 4; r++) bi1[tt][r] = a[r] + b[r];
        bin[tt] = *(const float4v*)(b_ih + 256 + nb);
        bhn[tt] = *(const float4v*)(b_hh + 256 + nb);
    }

    float4v h[2];
    h[0] = (float4v){0.f, 0.f, 0.f, 0.f};
    h[1] = (float4v){0.f, 0.f, 0.f, 0.f};

    // x prefetch: float4/thread, row = tid>>4, col = (tid&15)*4
    const int xrow = tid >> 4;
    const int xcol = (tid & 15) * 4;
    const float* xptr = x_seq + (size_t)(blk * 16 + xrow) * (Tn * Dn) + xcol;
    float4v xreg = *(const float4v*)xptr;

    const int rslot = m * 136 + q * 8;              // B-frag read base
    int wslot[2];                                    // C store slots (2 tiles)
    wslot[0] = m * 136 + 32 * w + 4 * q;
    wslot[1] = wslot[0] + 16;

    auto loadB = [&](const _Float16* base) -> Bfrag {
        const _Float16* p = base + rslot;
        Bfrag f;
        f.b0 = *(const half8v*)(p);
        f.b1 = *(const half8v*)(p + 32);
        f.b2 = *(const half8v*)(p + 64);
        f.b3 = *(const half8v*)(p + 96);
        return f;
    };
    // K=128 GEMM from register A-frags
    auto mm4 = [&](const half8v* Wf, const Bfrag& B, float4v cin) -> float4v {
        float4v o1 = cin;
        float4v o2 = {0.f, 0.f, 0.f, 0.f};
        o1 = __builtin_amdgcn_mfma_f32_16x16x32_f16(Wf[0], B.b0, o1, 0, 0, 0);
        o2 = __builtin_amdgcn_mfma_f32_16x16x32_f16(Wf[2], B.b2, o2, 0, 0, 0);
        o1 = __builtin_amdgcn_mfma_f32_16x16x32_f16(Wf[1], B.b1, o1, 0, 0, 0);
        o2 = __builtin_amdgcn_mfma_f32_16x16x32_f16(Wf[3], B.b3, o2, 0, 0, 0);
#pragma unroll
        for (int r = 0; r < 4; r++) o1[r] += o2[r];
        return o1;
    };
    // K=128 GEMM with A-frags from LDS weight rows (W1/W2)
    auto mm4_lds = [&](const _Float16* wlds, int n0t, const Bfrag& B, float4v cin) -> float4v {
        const _Float16* p = wlds + n0t * 136 + q * 8;
        half8v a0 = *(const half8v*)(p);
        half8v a1 = *(const half8v*)(p + 32);
        half8v a2 = *(const half8v*)(p + 64);
        half8v a3 = *(const half8v*)(p + 96);
        float4v o1 = cin;
        float4v o2 = {0.f, 0.f, 0.f, 0.f};
        o1 = __builtin_amdgcn_mfma_f32_16x16x32_f16(a0, B.b0, o1, 0, 0, 0);
        o2 = __builtin_amdgcn_mfma_f32_16x16x32_f16(a2, B.b2, o2, 0, 0, 0);
        o1 = __builtin_amdgcn_mfma_f32_16x16x32_f16(a1, B.b1, o1, 0, 0, 0);
        o2 = __builtin_amdgcn_mfma_f32_16x16x32_f16(a3, B.b3, o2, 0, 0, 0);
#pragma unroll
        for (int r = 0; r < 4; r++) o1[r] += o2[r];
        return o1;
    };

    float4v c1q[2];
    BAR();               // publish w1s/w2s, ts_l, c1s, vbuf(h0)
#pragma unroll
    for (int tt = 0; tt < 2; tt++)
#pragma unroll
        for (int r = 0; r < 4; r++) c1q[tt][r] = c1s[32 * w + 16 * tt + 4 * q + r];
    const float4v zero4 = {0.f, 0.f, 0.f, 0.f};

#pragma unroll 1
    for (int t = 0; t < Tn; ++t) {
        // ---- stage x_t ----
        {
            half4v xp = pack4(xreg);
            *(half4v*)(xbuf + xrow * 72 + xcol) = xp;
        }
        float tc  = ts_l[t];
        float tp  = (t > 0) ? ts_l[t - 1] : tc;
        float sub = (tc - tp) * 0.25f;      // dt / N_RK4 (0 at t=0)
        float hs  = 0.5f * sub;
        float s6  = sub * (1.0f / 6.0f);
        BAR();                              // publish xbuf + vbuf(h)
        if (t + 1 < Tn) xreg = *(const float4v*)(xptr + (t + 1) * Dn);

        // ---- interval A: gi = x Wih^T + biases  and  u_h = h W1^T + b1 ----
        float4v gi[3][2];
        {
            const _Float16* xp = xbuf + m * 72 + q * 8;
            half8v xf0 = *(const half8v*)(xp);
            half8v xf1 = *(const half8v*)(xp + 32);
#pragma unroll
            for (int g = 0; g < 3; g++) {
#pragma unroll
                for (int tt = 0; tt < 2; tt++) {
                    float4v acc = (g == 0) ? bi0[tt] : (g == 1) ? bi1[tt] : bin[tt];
                    acc = __builtin_amdgcn_mfma_f32_16x16x32_f16(wihf[g][tt][0], xf0, acc, 0, 0, 0);
                    acc = __builtin_amdgcn_mfma_f32_16x16x32_f16(wihf[g][tt][1], xf1, acc, 0, 0, 0);
                    gi[g][tt] = acc;
                }
            }
        }
        float4v u_h[2];
        {
            Bfrag hB = loadB(vbuf);
#pragma unroll
            for (int tt = 0; tt < 2; tt++)
                u_h[tt] = mm4_lds(w1s, 32 * w + 16 * tt + m, hB, b1q[tt]);
        }

        if (sub != 0.0f) {
            float4v Abar[2] = {zero4, zero4};
            float4v A[2], u[2];
#pragma unroll 1
            for (int s = 0; s < 4; s++) {
#pragma unroll
                for (int tt = 0; tt < 2; tt++) {
                    float4v a1 = tanh4(u_h[tt]);
                    A[tt] = a1;
                    *(half4v*)(abuf[0] + wslot[tt]) = pack4(a1);
                }
                BAR();
                {
                    Bfrag B = loadB(abuf[0]);
#pragma unroll
                    for (int tt = 0; tt < 2; tt++) {
                        float4v g = mm4(w21f[tt], B, c1q[tt]);      // a1 M^T + c1
#pragma unroll
                        for (int r = 0; r < 4; r++) u[tt][r] = u_h[tt][r] + hs * g[r];
                        float4v a2 = tanh4(u[tt]);
#pragma unroll
                        for (int r = 0; r < 4; r++) A[tt][r] += 2.0f * a2[r];
                        *(half4v*)(abuf[1] + wslot[tt]) = pack4(a2);
                    }
                }
                BAR();
                {
                    Bfrag B = loadB(abuf[1]);
#pragma unroll
                    for (int tt = 0; tt < 2; tt++) {
                        float4v g = mm4(w21f[tt], B, c1q[tt]);
#pragma unroll
                        for (int r = 0; r < 4; r++) u[tt][r] = u_h[tt][r] + hs * g[r];
                        float4v a3 = tanh4(u[tt]);
#pragma unroll
                        for (int r = 0; r < 4; r++) A[tt][r] += 2.0f * a3[r];
                        *(half4v*)(abuf[0] + wslot[tt]) = pack4(a3);
                    }
                }
                BAR();
                {
                    Bfrag B = loadB(abuf[0]);
#pragma unroll
                    for (int tt = 0; tt < 2; tt++) {
                        float4v g = mm4(w21f[tt], B, c1q[tt]);
#pragma unroll
                        for (int r = 0; r < 4; r++) u[tt][r] = u_h[tt][r] + sub * g[r];
                        float4v a4 = tanh4(u[tt]);
#pragma unroll
                        for (int r = 0; r < 4; r++) A[tt][r] += a4[r];
                        *(half4v*)(abuf[1] + wslot[tt]) = pack4(A[tt]);   // |A|<=6, fp16 ok
                    }
                }
                BAR();
                {
                    Bfrag B = loadB(abuf[1]);
#pragma unroll
                    for (int tt = 0; tt < 2; tt++) {
                        float4v g = mm4(w21f[tt], B, zero4);              // A M^T
#pragma unroll
                        for (int r = 0; r < 4; r++) {
                            u_h[tt][r]  += s6 * g[r] + sub * c1q[tt][r];
                            Abar[tt][r] += A[tt][r];
                        }
                    }
                }
            }
            // deferred h update: one W2-GEMM per step
#pragma unroll
            for (int tt = 0; tt < 2; tt++)
                *(half4v*)(abuf[0] + wslot[tt]) = pack4(Abar[tt]);        // |Abar|<=24, fp16 ok
            BAR();
            {
                Bfrag B = loadB(abuf[0]);
                float fourSub = 4.0f * sub;
#pragma unroll
                for (int tt = 0; tt < 2; tt++) {
                    float4v gw = mm4_lds(w2s, 32 * w + 16 * tt + m, B, zero4);
#pragma unroll
                    for (int r = 0; r < 4; r++) h[tt][r] += s6 * gw[r] + fourSub * b2q[tt][r];
                    *(half4v*)(vbuf + wslot[tt]) = pack4(h[tt]);          // publish post-RK h
                }
            }
            BAR();
        }
        // (sub==0: vbuf already holds h)

        // ---- gh = h Whh^T (+bhn for n-gate; r,z biases folded into gi) ----
        float4v gh[3][2];
        {
            Bfrag hB = loadB(vbuf);
#pragma unroll
            for (int g = 0; g < 3; g++) {
#pragma unroll
                for (int tt = 0; tt < 2; tt++) {
                    float4v acc = (g == 2) ? bhn[tt] : zero4;
                    acc = __builtin_amdgcn_mfma_f32_16x16x32_f16(whhf[g][tt][0], hB.b0, acc, 0, 0, 0);
                    acc = __builtin_amdgcn_mfma_f32_16x16x32_f16(whhf[g][tt][1], hB.b1, acc, 0, 0, 0);
                    acc = __builtin_amdgcn_mfma_f32_16x16x32_f16(whhf[g][tt][2], hB.b2, acc, 0, 0, 0);
                    acc = __builtin_amdgcn_mfma_f32_16x16x32_f16(whhf[g][tt][3], hB.b3, acc, 0, 0, 0);
                    gh[g][tt] = acc;
                }
            }
        }
        BAR();             // all waves done reading vbuf before GRU overwrite

        // ---- GRU (registers) ----
#pragma unroll
        for (int tt = 0; tt < 2; tt++) {
            half4v pk;
#pragma unroll
            for (int r = 0; r < 4; r++) {
                float rr = fast_sig(gi[0][tt][r] + gh[0][tt][r]);
                float zz = fast_sig(gi[1][tt][r] + gh[1][tt][r]);
                float nn = fast_tanh(gi[2][tt][r] + rr * gh[2][tt][r]);
                float hv = (1.0f - zz) * nn + zz * h[tt][r];
                h[tt][r] = hv;
                pk[r] = (_Float16)hv;
            }
            *(half4v*)(vbuf + wslot[tt]) = pk;
        }
        // loop-top barrier publishes vbuf
    }

    BAR();

    // ---- epilogue: mu / logvar ----
#pragma unroll
    for (int mat = 0; mat < 2; mat++) {
        const float* Wm = mat ? W_lv : W_mu;
        const float* bm = mat ? b_lv : b_mu;
        Bfrag hB = loadB(vbuf);
#pragma unroll
        for (int tt = 0; tt < 2; tt++) {
            int n0t = 32 * w + 16 * tt + m;
            float4v acc = *(const float4v*)(bm + 32 * w + 16 * tt + 4 * q);
            // NOTE: k offset must include q*8 (round-3 bug: it was dropped here,
            // corrupting only the epilogue GEMM -> absmax 2.62).
            half8v af0 = load_wfrag(Wm, Hn, n0t, 0  + q * 8);
            half8v af1 = load_wfrag(Wm, Hn, n0t, 32 + q * 8);
            half8v af2 = load_wfrag(Wm, Hn, n0t, 64 + q * 8);
            half8v af3 = load_wfrag(Wm, Hn, n0t, 96 + q * 8);
            acc = __builtin_amdgcn_mfma_f32_16x16x32_f16(af0, hB.b0, acc, 0, 0, 0);
            acc = __builtin_amdgcn_mfma_f32_16x16x32_f16(af1, hB.b1, acc, 0, 0, 0);
            acc = __builtin_amdgcn_mfma_f32_16x16x32_f16(af2, hB.b2, acc, 0, 0, 0);
            acc = __builtin_amdgcn_mfma_f32_16x16x32_f16(af3, hB.b3, acc, 0, 0, 0);
            *(float4v*)(out + (size_t)mat * Bn * Hn + (size_t)(blk * 16 + m) * Hn + 32 * w + 16 * tt + 4 * q) = acc;
        }
    }
}

extern "C" void kernel_launch(void* const* d_in, const int* in_sizes, int n_in,
                              void* d_out, int out_size, void* d_ws, size_t ws_size,
                              hipStream_t stream) {
    (void)in_sizes; (void)n_in; (void)d_ws; (void)ws_size; (void)out_size;
    odernn_kernel<<<dim3(Bn / 16), dim3(256), 0, stream>>>(
        (const float*)d_in[0],  (const float*)d_in[1],  (const float*)d_in[2],
        (const float*)d_in[3],  (const float*)d_in[4],  (const float*)d_in[5],
        (const float*)d_in[6],  (const float*)d_in[7],  (const float*)d_in[8],
        (const float*)d_in[9],  (const float*)d_in[10], (const float*)d_in[11],
        (const float*)d_in[12], (const float*)d_in[13], (float*)d_out);
}

// Round 5
// 806.817 us; speedup vs baseline: 2.5575x; 1.1421x over previous
//
#include <hip/hip_runtime.h>

#define Bn 4096
#define Tn 100
#define Dn 64
#define Hn 128

typedef _Float16 half8v __attribute__((ext_vector_type(8)));
typedef _Float16 half4v __attribute__((ext_vector_type(4)));
typedef float    float4v __attribute__((ext_vector_type(4)));
typedef float    float2v __attribute__((ext_vector_type(2)));

// barrier: LDS-only drain (no vmcnt(0) -> x prefetch stays in flight)
#define BAR() asm volatile("s_waitcnt lgkmcnt(0)\ns_barrier" ::: "memory")

__device__ __forceinline__ float fast_tanh(float x) {
    float e = __expf(x + x);
    return 1.0f - 2.0f * __builtin_amdgcn_rcpf(e + 1.0f);
}
__device__ __forceinline__ float fast_sig(float x) {
    return __builtin_amdgcn_rcpf(1.0f + __expf(-x));
}
__device__ __forceinline__ float4v tanh4(float4v u) {
    float4v a;
#pragma unroll
    for (int r = 0; r < 4; r++) a[r] = fast_tanh(u[r]);
    return a;
}
__device__ __forceinline__ half4v pack4(float4v v) {
    half4v p;
#pragma unroll
    for (int r = 0; r < 4; r++) p[r] = (_Float16)v[r];
    return p;
}

// A-operand fragment of stationary weight W [n x ld]: lane gets W[n][k..k+7] fp32->fp16.
__device__ __forceinline__ half8v load_wfrag(const float* __restrict__ W, int ld, int n, int k) {
    const float* p = W + (size_t)n * ld + k;
    float4v a = *(const float4v*)p;
    float4v b = *(const float4v*)(p + 4);
    half8v r;
    r[0] = (_Float16)a[0]; r[1] = (_Float16)a[1]; r[2] = (_Float16)a[2]; r[3] = (_Float16)a[3];
    r[4] = (_Float16)b[0]; r[5] = (_Float16)b[1]; r[6] = (_Float16)b[2]; r[7] = (_Float16)b[3];
    return r;
}

struct Bfrag { half8v b0, b1, b2, b3; };

// Persistent ODE-RNN kernel. 256 blocks x 512 threads (8 waves, 2/SIMD) — the
// proven round-0 geometry (grid == CU count; co-residency impossible, so all
// stall-filling must be intra-block). Changes vs round 0:
//  * Rotated-column LDS layout: logical [m][n] stored at col (n+16m)&127.
//    Spreads the exchange's ds_read_b128 / ds_write bank groups to ~2-way
//    (round-0 linear layout measured 7.9e7 conflict-cycles/dispatch).
//  * RK4 substep 3 skips its trailing A-exchange (only fed the dead u_h
//    update): 20 -> 18 barriers/step, 16 -> 15 M-GEMMs.
//  * vbuf ping-pong across steps: GRU writes h_new to the other buffer,
//    removing the post-gh WAR barrier.
//  * gi (x-GEMM) moved off the prologue critical path into the gh slot.
__global__ __launch_bounds__(512) void odernn_kernel(
    const float* __restrict__ x_seq, const float* __restrict__ t_seq,
    const float* __restrict__ W1,   const float* __restrict__ b1,
    const float* __restrict__ W2,   const float* __restrict__ b2,
    const float* __restrict__ W_ih, const float* __restrict__ W_hh,
    const float* __restrict__ b_ih, const float* __restrict__ b_hh,
    const float* __restrict__ W_mu, const float* __restrict__ b_mu,
    const float* __restrict__ W_lv, const float* __restrict__ b_lv,
    float* __restrict__ out)
{
    __shared__ _Float16 vbuf[2][16 * 136];   // h exchange, ping-pong across steps
    __shared__ _Float16 abuf[2][16 * 136];   // a_i / A / Abar exchange, ping-pong
    __shared__ _Float16 xbuf[16 * 72];       // x_t staging
    __shared__ float    ts_l[Tn];
    __shared__ float    c1s[Hn];             // c1 = b2 @ W1^T

    const int tid  = threadIdx.x;
    const int lane = tid & 63;
    const int w    = tid >> 6;        // wave 0..7 = n-tile owner
    const int q    = lane >> 4;
    const int m    = lane & 15;
    const int rot  = 16 * m;          // column rotation (bank spread)
    const int blk  = blockIdx.x;

    if (tid < Tn) ts_l[tid] = t_seq[tid];
    for (int i = tid; i < 16 * 136; i += 512) vbuf[0][i] = (_Float16)0.f;  // h0 = 0
    if (tid < Hn) {                                   // c1[n] = dot(b2, W1[n][:])
        float acc = 0.f;
        const float* r1 = W1 + (size_t)tid * Hn;
#pragma unroll 4
        for (int j = 0; j < Hn; j++) acc += b2[j] * r1[j];
        c1s[tid] = acc;
    }

    // ---- stationary weight fragments (register-resident) ----
    const int n0 = 16 * w + m;
    half8v w1f[4], w2f[4], whhf[3][4], wihf[3][2];
#pragma unroll
    for (int kt = 0; kt < 4; kt++) {
        w1f[kt] = load_wfrag(W1, Hn, n0, 32 * kt + q * 8);
        w2f[kt] = load_wfrag(W2, Hn, n0, 32 * kt + q * 8);
    }
#pragma unroll
    for (int g = 0; g < 3; g++) {                 // 0=r, 1=z, 2=n gate
        int n = 128 * g + n0;
#pragma unroll
        for (int kt = 0; kt < 4; kt++) whhf[g][kt] = load_wfrag(W_hh, Hn, n, 32 * kt + q * 8);
#pragma unroll
        for (int kt = 0; kt < 2; kt++) wihf[g][kt] = load_wfrag(W_ih, Dn, n, 32 * kt + q * 8);
    }
    float4v b1q = *(const float4v*)(b1 + 16 * w + q * 4);
    float4v b2q = *(const float4v*)(b2 + 16 * w + q * 4);
    // r,z gate b_hh folded into gi C-in; n-gate keeps separate biases
    float4v bi0, bi1, bin, bhn;
    {
        float4v a, b;
        a = *(const float4v*)(b_ih + 0   + 16 * w + q * 4);
        b = *(const float4v*)(b_hh + 0   + 16 * w + q * 4);
#pragma unroll
        for (int r = 0; r < 4; r++) bi0[r] = a[r] + b[r];
        a = *(const float4v*)(b_ih + 128 + 16 * w + q * 4);
        b = *(const float4v*)(b_hh + 128 + 16 * w + q * 4);
#pragma unroll
        for (int r = 0; r < 4; r++) bi1[r] = a[r] + b[r];
        bin = *(const float4v*)(b_ih + 256 + 16 * w + q * 4);
        bhn = *(const float4v*)(b_hh + 256 + 16 * w + q * 4);
    }

    // ---- M = W1 @ W2 fragments (one-time fp32 dot; A-layout) ----
    float4v accM[4][2];
#pragma unroll
    for (int kt = 0; kt < 4; kt++) {
        float4v zz = {0.f, 0.f, 0.f, 0.f};
        accM[kt][0] = zz; accM[kt][1] = zz;
    }
    {
        const float* w1row = W1 + (size_t)n0 * Hn;
        for (int j = 0; j < Hn; j++) {
            float w1v = w1row[j];
            const float* w2r = W2 + (size_t)j * Hn + q * 8;
#pragma unroll
            for (int kt = 0; kt < 4; kt++) {
                float4v aa = *(const float4v*)(w2r + 32 * kt);
                float4v bb = *(const float4v*)(w2r + 32 * kt + 4);
#pragma unroll
                for (int r = 0; r < 4; r++) {
                    accM[kt][0][r] += w1v * aa[r];
                    accM[kt][1][r] += w1v * bb[r];
                }
            }
        }
    }
    half8v w21f[4];
#pragma unroll
    for (int kt = 0; kt < 4; kt++) {
#pragma unroll
        for (int r = 0; r < 4; r++) {
            w21f[kt][r]     = (_Float16)accM[kt][0][r];
            w21f[kt][r + 4] = (_Float16)accM[kt][1][r];
        }
    }

    float4v h = {0.f, 0.f, 0.f, 0.f};   // C-layout: n = 16w+4q+r, col m

    // x prefetch: 2 floats/thread (512 thr x 2 = 16 rows x 64 cols)
    const int xrow = tid >> 5;
    const int xcol = (tid & 31) * 2;
    const float* xptr = x_seq + (size_t)(blk * 16 + xrow) * (Tn * Dn) + xcol;
    float2v xreg = *(const float2v*)xptr;

    // rotated store/read slots
    const int wslot = m * 136 + ((16 * w + 4 * q + rot) & 127);   // C store (4-run)
    const int xws   = xrow * 72 + ((xcol + 16 * xrow) & 63);      // x stage (2-run)

    // B-frag read: logical k-chunks {0,32,64,96}+8q, each rotated by 16m
    auto loadB = [&](const _Float16* base) -> Bfrag {
        const _Float16* p = base + m * 136;
        Bfrag f;
        f.b0 = *(const half8v*)(p + ((     8 * q + rot) & 127));
        f.b1 = *(const half8v*)(p + ((32 + 8 * q + rot) & 127));
        f.b2 = *(const half8v*)(p + ((64 + 8 * q + rot) & 127));
        f.b3 = *(const half8v*)(p + ((96 + 8 * q + rot) & 127));
        return f;
    };
    // K=128 GEMM, 2 independent MFMA chains of 2
    auto mm4 = [&](const half8v* Wf, const Bfrag& B, float4v cin) -> float4v {
        float4v o1 = cin;
        float4v o2 = {0.f, 0.f, 0.f, 0.f};
        o1 = __builtin_amdgcn_mfma_f32_16x16x32_f16(Wf[0], B.b0, o1, 0, 0, 0);
        o2 = __builtin_amdgcn_mfma_f32_16x16x32_f16(Wf[2], B.b2, o2, 0, 0, 0);
        o1 = __builtin_amdgcn_mfma_f32_16x16x32_f16(Wf[1], B.b1, o1, 0, 0, 0);
        o2 = __builtin_amdgcn_mfma_f32_16x16x32_f16(Wf[3], B.b3, o2, 0, 0, 0);
#pragma unroll
        for (int r = 0; r < 4; r++) o1[r] += o2[r];
        return o1;
    };

    _Float16* vc = vbuf[0];     // current h buffer
    _Float16* vn = vbuf[1];     // next-step h buffer

    float4v c1q;
    BAR();               // publish ts_l, c1s, vbuf[0](h0)
#pragma unroll
    for (int r = 0; r < 4; r++) c1q[r] = c1s[16 * w + q * 4 + r];
    const float4v zero4 = {0.f, 0.f, 0.f, 0.f};

#pragma unroll 1
    for (int t = 0; t < Tn; ++t) {
        // ---- stage x_t (rotated) ----
        xbuf[xws]     = (_Float16)xreg[0];
        xbuf[xws + 1] = (_Float16)xreg[1];
        float tc  = ts_l[t];
        float tp  = (t > 0) ? ts_l[t - 1] : tc;
        float sub = (tc - tp) * 0.25f;      // dt / N_RK4 (0 at t=0)
        float hs  = 0.5f * sub;
        float s6  = sub * (1.0f / 6.0f);
        BAR();                              // publish xbuf + vc(h)
        if (t + 1 < Tn) xreg = *(const float2v*)(xptr + (t + 1) * Dn);

        // ---- u_h = h W1^T + b1 (critical path; gi deferred to gh slot) ----
        float4v u_h = mm4(w1f, loadB(vc), b1q);

        if (sub != 0.0f) {
            float4v Abar = zero4;
#pragma unroll 1
            for (int s = 0; s < 4; s++) {
                float4v a1 = tanh4(u_h);
                float4v A  = a1;
                *(half4v*)(abuf[0] + wslot) = pack4(a1);
                BAR();
                float4v g = mm4(w21f, loadB(abuf[0]), c1q);     // a1 M^T + c1
                float4v u;
#pragma unroll
                for (int r = 0; r < 4; r++) u[r] = u_h[r] + hs * g[r];
                float4v a2 = tanh4(u);
#pragma unroll
                for (int r = 0; r < 4; r++) A[r] += 2.0f * a2[r];
                *(half4v*)(abuf[1] + wslot) = pack4(a2);
                BAR();
                g = mm4(w21f, loadB(abuf[1]), c1q);
#pragma unroll
                for (int r = 0; r < 4; r++) u[r] = u_h[r] + hs * g[r];
                float4v a3 = tanh4(u);
#pragma unroll
                for (int r = 0; r < 4; r++) A[r] += 2.0f * a3[r];
                *(half4v*)(abuf[0] + wslot) = pack4(a3);
                BAR();
                g = mm4(w21f, loadB(abuf[0]), c1q);
#pragma unroll
                for (int r = 0; r < 4; r++) u[r] = u_h[r] + sub * g[r];
                float4v a4 = tanh4(u);
#pragma unroll
                for (int r = 0; r < 4; r++) {
                    A[r]    += a4[r];
                    Abar[r] += A[r];
                }
                if (s < 3) {                 // s=3: A M^T only fed the dead u_h update — skip
                    *(half4v*)(abuf[1] + wslot) = pack4(A);     // |A| <= 6, fp16 ok
                    BAR();
                    g = mm4(w21f, loadB(abuf[1]), zero4);       // A M^T
#pragma unroll
                    for (int r = 0; r < 4; r++) u_h[r] += s6 * g[r] + sub * c1q[r];
                }
            }
            // deferred h update: one W2-GEMM per step
            *(half4v*)(abuf[1] + wslot) = pack4(Abar);          // |Abar| <= 24, fp16 ok
            BAR();
            float4v gw = mm4(w2f, loadB(abuf[1]), zero4);
            float fourSub = 4.0f * sub;
#pragma unroll
            for (int r = 0; r < 4; r++) h[r] += s6 * gw[r] + fourSub * b2q[r];
            *(half4v*)(vc + wslot) = pack4(h);                  // publish post-RK h
            BAR();
        }
        // (sub==0: vc already holds h)

        // ---- gi = x Wih^T + biases  and  gh = h Whh^T (merged, 18 MFMA) ----
        float4v gi[3], gh[3];
        {
            half8v xf0 = *(const half8v*)(xbuf + m * 72 + ((     8 * q + rot) & 63));
            half8v xf1 = *(const half8v*)(xbuf + m * 72 + ((32 + 8 * q + rot) & 63));
            Bfrag hB = loadB(vc);
#pragma unroll
            for (int g = 0; g < 3; g++) {
                float4v acc = (g == 0) ? bi0 : (g == 1) ? bi1 : bin;
                acc = __builtin_amdgcn_mfma_f32_16x16x32_f16(wihf[g][0], xf0, acc, 0, 0, 0);
                acc = __builtin_amdgcn_mfma_f32_16x16x32_f16(wihf[g][1], xf1, acc, 0, 0, 0);
                gi[g] = acc;
                float4v a2c = (g == 2) ? bhn : zero4;
                a2c = __builtin_amdgcn_mfma_f32_16x16x32_f16(whhf[g][0], hB.b0, a2c, 0, 0, 0);
                a2c = __builtin_amdgcn_mfma_f32_16x16x32_f16(whhf[g][1], hB.b1, a2c, 0, 0, 0);
                a2c = __builtin_amdgcn_mfma_f32_16x16x32_f16(whhf[g][2], hB.b2, a2c, 0, 0, 0);
                a2c = __builtin_amdgcn_mfma_f32_16x16x32_f16(whhf[g][3], hB.b3, a2c, 0, 0, 0);
                gh[g] = a2c;
            }
        }
        // no barrier: GRU writes the OTHER vbuf (ping-pong removes WAR hazard)

        // ---- GRU (registers) ----
        {
            half4v pk;
#pragma unroll
            for (int r = 0; r < 4; r++) {
                float rr = fast_sig(gi[0][r] + gh[0][r]);
                float zz = fast_sig(gi[1][r] + gh[1][r]);
                float nn = fast_tanh(gi[2][r] + rr * gh[2][r]);
                float hv = (1.0f - zz) * nn + zz * h[r];
                h[r] = hv;
                pk[r] = (_Float16)hv;
            }
            *(half4v*)(vn + wslot) = pk;
        }
        // swap buffers; loop-top barrier publishes vn as the new vc
        _Float16* tmp = vc; vc = vn; vn = tmp;
    }

    BAR();

    // ---- epilogue: mu / logvar (vc holds final h after last swap) ----
#pragma unroll
    for (int mat = 0; mat < 2; mat++) {
        const float* Wm = mat ? W_lv : W_mu;
        const float* bm = mat ? b_lv : b_mu;
        float4v acc = *(const float4v*)(bm + 16 * w + q * 4);
        Bfrag hB = loadB(vc);
#pragma unroll
        for (int kt = 0; kt < 4; kt++) {
            half8v af = load_wfrag(Wm, Hn, n0, 32 * kt + q * 8);   // k MUST include q*8
            const half8v* bf = (kt == 0) ? &hB.b0 : (kt == 1) ? &hB.b1 : (kt == 2) ? &hB.b2 : &hB.b3;
            acc = __builtin_amdgcn_mfma_f32_16x16x32_f16(af, *bf, acc, 0, 0, 0);
        }
        *(float4v*)(out + (size_t)mat * Bn * Hn + (size_t)(blk * 16 + m) * Hn + 16 * w + q * 4) = acc;
    }
}

extern "C" void kernel_launch(void* const* d_in, const int* in_sizes, int n_in,
                              void* d_out, int out_size, void* d_ws, size_t ws_size,
                              hipStream_t stream) {
    (void)in_sizes; (void)n_in; (void)d_ws; (void)ws_size; (void)out_size;
    odernn_kernel<<<dim3(Bn / 16), dim3(512), 0, stream>>>(
        (const float*)d_in[0],  (const float*)d_in[1],  (const float*)d_in[2],
        (const float*)d_in[3],  (const float*)d_in[4],  (const float*)d_in[5],
        (const float*)d_in[6],  (const float*)d_in[7],  (const float*)d_in[8],
        (const float*)d_in[9],  (const float*)d_in[10], (const float*)d_in[11],
        (const float*)d_in[12], (const float*)d_in[13], (float*)d_out);
}

// Round 7
// 760.431 us; speedup vs baseline: 2.7135x; 1.0610x over previous
//
#include <hip/hip_runtime.h>

#define Bn 4096
#define Tn 100
#define Dn 64
#define Hn 128

#define L2C  2.8853900817779268f   // 2*log2(e)
#define NL2E 1.4426950408889634f   // log2(e)

typedef _Float16 half8v __attribute__((ext_vector_type(8)));
typedef _Float16 half4v __attribute__((ext_vector_type(4)));
typedef __fp16   fp16x2 __attribute__((ext_vector_type(2)));   // cvt_pkrtz native type
typedef float    float4v __attribute__((ext_vector_type(4)));
typedef float    float2v __attribute__((ext_vector_type(2)));

// barrier: LDS-only drain (no vmcnt(0) -> x prefetch stays in flight)
#define BAR() asm volatile("s_waitcnt lgkmcnt(0)\ns_barrier" ::: "memory")

// tanh(u) where uL = u * 2*log2(e)  (L-scaled domain; scaling folded into weights)
__device__ __forceinline__ float tanhL(float uL) {
    return 1.0f - 2.0f * __builtin_amdgcn_rcpf(__builtin_amdgcn_exp2f(uL) + 1.0f);
}
// sigma(x) where sN = -x * log2(e)
__device__ __forceinline__ float sigN(float sN) {
    return __builtin_amdgcn_rcpf(1.0f + __builtin_amdgcn_exp2f(sN));
}
__device__ __forceinline__ float4v tanh4L(float4v uL) {
    float4v a;
#pragma unroll
    for (int r = 0; r < 4; r++) a[r] = tanhL(uL[r]);
    return a;
}
__device__ __forceinline__ half4v pack4(float4v v) {
    fp16x2 lo = __builtin_amdgcn_cvt_pkrtz(v[0], v[1]);   // v_cvt_pkrtz_f16_f32
    fp16x2 hi = __builtin_amdgcn_cvt_pkrtz(v[2], v[3]);
    struct P { fp16x2 a, b; } pp{lo, hi};
    return __builtin_bit_cast(half4v, pp);
}

// A-operand fragment of stationary weight W [n x ld], fp32 -> fp16, optional scale.
__device__ __forceinline__ half8v load_wfrag_s(const float* __restrict__ W, int ld, int n, int k, float s) {
    const float* p = W + (size_t)n * ld + k;
    float4v a = *(const float4v*)p * s;
    float4v b = *(const float4v*)(p + 4) * s;
    half8v r;
    r[0] = (_Float16)a[0]; r[1] = (_Float16)a[1]; r[2] = (_Float16)a[2]; r[3] = (_Float16)a[3];
    r[4] = (_Float16)b[0]; r[5] = (_Float16)b[1]; r[6] = (_Float16)b[2]; r[7] = (_Float16)b[3];
    return r;
}
__device__ __forceinline__ half8v load_wfrag(const float* __restrict__ W, int ld, int n, int k) {
    return load_wfrag_s(W, ld, n, k, 1.0f);
}

struct Bfrag { half8v b0, b1, b2, b3; };

// Persistent ODE-RNN kernel. 256 blocks x 512 threads (8 waves, 2/SIMD) — the
// proven round-0 geometry. Round-6/7 changes (VALU diet; structure unchanged):
//  * LINEAR LDS slots (round-5 rotation proven conflict-neutral; rotation only
//    cost VALU).
//  * exp2 pre-scaling: u_h kept in 2*log2(e)-scaled units via one-time weight/
//    bias fragment scaling (W1,Whh_n,Wih_n,b* x L2C; r/z gates x -log2e) ->
//    tanh = 1-2*rcp(exp2(u)+1), sigma = rcp(1+exp2(s)), no per-elem muls.
//  * cvt_pkrtz packs (2 inst / 4 values) via __fp16x2 + bit_cast (r6 compile fix).
//  * float4v vector expressions for all updates (invites v_pk_fma_f32).
// Kept from round 5: skip s=3 trailing A-exchange, vbuf ping-pong (no post-gh
// barrier), gi merged into gh slot.
__global__ __launch_bounds__(512) void odernn_kernel(
    const float* __restrict__ x_seq, const float* __restrict__ t_seq,
    const float* __restrict__ W1,   const float* __restrict__ b1,
    const float* __restrict__ W2,   const float* __restrict__ b2,
    const float* __restrict__ W_ih, const float* __restrict__ W_hh,
    const float* __restrict__ b_ih, const float* __restrict__ b_hh,
    const float* __restrict__ W_mu, const float* __restrict__ b_mu,
    const float* __restrict__ W_lv, const float* __restrict__ b_lv,
    float* __restrict__ out)
{
    __shared__ _Float16 vbuf[2][16 * 136];   // h exchange, ping-pong across steps
    __shared__ _Float16 abuf[2][16 * 136];   // a_i / A / Abar exchange, ping-pong
    __shared__ _Float16 xbuf[16 * 72];       // x_t staging
    __shared__ float    ts_l[Tn];
    __shared__ float    c1s[Hn];             // c1 = b2 @ W1^T (RAW units)

    const int tid  = threadIdx.x;
    const int lane = tid & 63;
    const int w    = tid >> 6;        // wave 0..7 = n-tile owner
    const int q    = lane >> 4;
    const int m    = lane & 15;
    const int blk  = blockIdx.x;

    if (tid < Tn) ts_l[tid] = t_seq[tid];
    for (int i = tid; i < 16 * 136; i += 512) vbuf[0][i] = (_Float16)0.f;  // h0 = 0
    if (tid < Hn) {                                   // c1[n] = dot(b2, W1[n][:])
        float acc = 0.f;
        const float* r1 = W1 + (size_t)tid * Hn;
#pragma unroll 4
        for (int j = 0; j < Hn; j++) acc += b2[j] * r1[j];
        c1s[tid] = acc;
    }

    // ---- stationary weight fragments (register-resident, pre-scaled) ----
    const int n0 = 16 * w + m;
    half8v w1f[4], w2f[4], whhf[3][4], wihf[3][2];
#pragma unroll
    for (int kt = 0; kt < 4; kt++) {
        w1f[kt] = load_wfrag_s(W1, Hn, n0, 32 * kt + q * 8, L2C);   // L-scaled
        w2f[kt] = load_wfrag  (W2, Hn, n0, 32 * kt + q * 8);        // raw
    }
#pragma unroll
    for (int g = 0; g < 3; g++) {                 // 0=r, 1=z (x -log2e), 2=n (x L2C)
        float gs = (g == 2) ? L2C : -NL2E;
        int n = 128 * g + n0;
#pragma unroll
        for (int kt = 0; kt < 4; kt++) whhf[g][kt] = load_wfrag_s(W_hh, Hn, n, 32 * kt + q * 8, gs);
#pragma unroll
        for (int kt = 0; kt < 2; kt++) wihf[g][kt] = load_wfrag_s(W_ih, Dn, n, 32 * kt + q * 8, gs);
    }
    float4v b1q = *(const float4v*)(b1 + 16 * w + q * 4) * L2C;     // L-scaled
    float4v b2q = *(const float4v*)(b2 + 16 * w + q * 4);           // raw
    // r,z gate b_hh folded into gi C-in; all gate biases pre-scaled
    float4v bi0, bi1, bin, bhn;
    {
        float4v a, b;
        a = *(const float4v*)(b_ih + 0   + 16 * w + q * 4);
        b = *(const float4v*)(b_hh + 0   + 16 * w + q * 4);
        bi0 = (a + b) * (-NL2E);
        a = *(const float4v*)(b_ih + 128 + 16 * w + q * 4);
        b = *(const float4v*)(b_hh + 128 + 16 * w + q * 4);
        bi1 = (a + b) * (-NL2E);
        bin = *(const float4v*)(b_ih + 256 + 16 * w + q * 4) * L2C;
        bhn = *(const float4v*)(b_hh + 256 + 16 * w + q * 4) * L2C;
    }

    // ---- M = W1 @ W2 fragments (one-time fp32 dot; RAW — feeds raw g) ----
    float4v accM[4][2];
#pragma unroll
    for (int kt = 0; kt < 4; kt++) {
        float4v zz = {0.f, 0.f, 0.f, 0.f};
        accM[kt][0] = zz; accM[kt][1] = zz;
    }
    {
        const float* w1row = W1 + (size_t)n0 * Hn;
        for (int j = 0; j < Hn; j++) {
            float w1v = w1row[j];
            const float* w2r = W2 + (size_t)j * Hn + q * 8;
#pragma unroll
            for (int kt = 0; kt < 4; kt++) {
                float4v aa = *(const float4v*)(w2r + 32 * kt);
                float4v bb = *(const float4v*)(w2r + 32 * kt + 4);
                accM[kt][0] += w1v * aa;
                accM[kt][1] += w1v * bb;
            }
        }
    }
    half8v w21f[4];
#pragma unroll
    for (int kt = 0; kt < 4; kt++) {
#pragma unroll
        for (int r = 0; r < 4; r++) {
            w21f[kt][r]     = (_Float16)accM[kt][0][r];
            w21f[kt][r + 4] = (_Float16)accM[kt][1][r];
        }
    }

    float4v h = {0.f, 0.f, 0.f, 0.f};   // RAW units. C-layout: n = 16w+4q+r, col m

    // x prefetch: 2 floats/thread (512 thr x 2 = 16 rows x 64 cols)
    const int xrow = tid >> 5;
    const int xcol = (tid & 31) * 2;
    const float* xptr = x_seq + (size_t)(blk * 16 + xrow) * (Tn * Dn) + xcol;
    float2v xreg = *(const float2v*)xptr;

    // linear store/read slots
    const int wslot = m * 136 + 16 * w + 4 * q;     // C store
    const int rslot = m * 136 + q * 8;              // B-frag read base
    const int xws   = xrow * 72 + xcol;

    auto loadB = [&](const _Float16* base) -> Bfrag {
        const _Float16* p = base + rslot;
        Bfrag f;
        f.b0 = *(const half8v*)(p);
        f.b1 = *(const half8v*)(p + 32);
        f.b2 = *(const half8v*)(p + 64);
        f.b3 = *(const half8v*)(p + 96);
        return f;
    };
    // K=128 GEMM, 2 independent MFMA chains of 2
    auto mm4 = [&](const half8v* Wf, const Bfrag& B, float4v cin) -> float4v {
        float4v o1 = cin;
        float4v o2 = {0.f, 0.f, 0.f, 0.f};
        o1 = __builtin_amdgcn_mfma_f32_16x16x32_f16(Wf[0], B.b0, o1, 0, 0, 0);
        o2 = __builtin_amdgcn_mfma_f32_16x16x32_f16(Wf[2], B.b2, o2, 0, 0, 0);
        o1 = __builtin_amdgcn_mfma_f32_16x16x32_f16(Wf[1], B.b1, o1, 0, 0, 0);
        o2 = __builtin_amdgcn_mfma_f32_16x16x32_f16(Wf[3], B.b3, o2, 0, 0, 0);
        return o1 + o2;
    };

    _Float16* vc = vbuf[0];     // current h buffer
    _Float16* vn = vbuf[1];     // next-step h buffer

    float4v c1q;                // RAW
    BAR();               // publish ts_l, c1s, vbuf[0](h0)
#pragma unroll
    for (int r = 0; r < 4; r++) c1q[r] = c1s[16 * w + q * 4 + r];
    const float4v zero4 = {0.f, 0.f, 0.f, 0.f};

#pragma unroll 1
    for (int t = 0; t < Tn; ++t) {
        // ---- stage x_t ----
        xbuf[xws]     = (_Float16)xreg[0];
        xbuf[xws + 1] = (_Float16)xreg[1];
        float tc   = ts_l[t];
        float tp   = (t > 0) ? ts_l[t - 1] : tc;
        float sub  = (tc - tp) * 0.25f;        // dt / N_RK4 (0 at t=0)
        float hsL  = sub * (0.5f * L2C);       // L-scaled coefficients
        float subL = sub * L2C;
        float s6L  = sub * (L2C / 6.0f);
        float s6   = sub * (1.0f / 6.0f);      // raw (h update)
        BAR();                                 // publish xbuf + vc(h)
        if (t + 1 < Tn) xreg = *(const float2v*)(xptr + (t + 1) * Dn);

        // ---- u_h = L*(h W1^T + b1) via pre-scaled fragments ----
        float4v u_h = mm4(w1f, loadB(vc), b1q);

        if (sub != 0.0f) {
            float4v Abar = zero4;
#pragma unroll 1
            for (int s = 0; s < 4; s++) {
                float4v a1 = tanh4L(u_h);
                float4v A  = a1;
                *(half4v*)(abuf[0] + wslot) = pack4(a1);
                BAR();
                float4v g = mm4(w21f, loadB(abuf[0]), c1q);     // a1 M^T + c1 (raw)
                float4v u = u_h + hsL * g;
                float4v a2 = tanh4L(u);
                A += 2.0f * a2;
                *(half4v*)(abuf[1] + wslot) = pack4(a2);
                BAR();
                g = mm4(w21f, loadB(abuf[1]), c1q);
                u = u_h + hsL * g;
                float4v a3 = tanh4L(u);
                A += 2.0f * a3;
                *(half4v*)(abuf[0] + wslot) = pack4(a3);
                BAR();
                g = mm4(w21f, loadB(abuf[0]), c1q);
                u = u_h + subL * g;
                float4v a4 = tanh4L(u);
                A += a4;
                Abar += A;
                if (s < 3) {                 // s=3: A M^T only fed the dead u_h update — skip
                    *(half4v*)(abuf[1] + wslot) = pack4(A);     // |A| <= 6, fp16 ok
                    BAR();
                    g = mm4(w21f, loadB(abuf[1]), zero4);       // A M^T (raw)
                    u_h += s6L * g + subL * c1q;
                }
            }
            // deferred h update: one W2-GEMM per step (raw units)
            *(half4v*)(abuf[1] + wslot) = pack4(Abar);          // |Abar| <= 24, fp16 ok
            BAR();
            float4v gw = mm4(w2f, loadB(abuf[1]), zero4);
            h += s6 * gw + (4.0f * sub) * b2q;
            *(half4v*)(vc + wslot) = pack4(h);                  // publish post-RK h
            BAR();
        }
        // (sub==0: vc already holds h)

        // ---- gi = x Wih^T + biases  and  gh = h Whh^T (merged, pre-scaled) ----
        float4v gi[3], gh[3];
        {
            half8v xf0 = *(const half8v*)(xbuf + m * 72 + q * 8);
            half8v xf1 = *(const half8v*)(xbuf + m * 72 + q * 8 + 32);
            Bfrag hB = loadB(vc);
#pragma unroll
            for (int g = 0; g < 3; g++) {
                float4v acc = (g == 0) ? bi0 : (g == 1) ? bi1 : bin;
                acc = __builtin_amdgcn_mfma_f32_16x16x32_f16(wihf[g][0], xf0, acc, 0, 0, 0);
                acc = __builtin_amdgcn_mfma_f32_16x16x32_f16(wihf[g][1], xf1, acc, 0, 0, 0);
                gi[g] = acc;
                float4v a2c = (g == 2) ? bhn : zero4;
                a2c = __builtin_amdgcn_mfma_f32_16x16x32_f16(whhf[g][0], hB.b0, a2c, 0, 0, 0);
                a2c = __builtin_amdgcn_mfma_f32_16x16x32_f16(whhf[g][1], hB.b1, a2c, 0, 0, 0);
                a2c = __builtin_amdgcn_mfma_f32_16x16x32_f16(whhf[g][2], hB.b2, a2c, 0, 0, 0);
                a2c = __builtin_amdgcn_mfma_f32_16x16x32_f16(whhf[g][3], hB.b3, a2c, 0, 0, 0);
                gh[g] = a2c;
            }
        }
        // no barrier: GRU writes the OTHER vbuf (ping-pong removes WAR hazard)

        // ---- GRU (registers; gates in scaled domains) ----
        {
            float4v hv;
#pragma unroll
            for (int r = 0; r < 4; r++) {
                float rr = sigN(gi[0][r] + gh[0][r]);           // pre-scaled by -log2e
                float zz = sigN(gi[1][r] + gh[1][r]);
                float nn = tanhL(gi[2][r] + rr * gh[2][r]);     // pre-scaled by L2C
                hv[r] = nn + zz * (h[r] - nn);
            }
            h = hv;
            *(half4v*)(vn + wslot) = pack4(hv);
        }
        // swap buffers; loop-top barrier publishes vn as the new vc
        _Float16* tmp = vc; vc = vn; vn = tmp;
    }

    BAR();

    // ---- epilogue: mu / logvar (vc holds final h after last swap; raw) ----
#pragma unroll
    for (int mat = 0; mat < 2; mat++) {
        const float* Wm = mat ? W_lv : W_mu;
        const float* bm = mat ? b_lv : b_mu;
        float4v acc = *(const float4v*)(bm + 16 * w + q * 4);
        Bfrag hB = loadB(vc);
#pragma unroll
        for (int kt = 0; kt < 4; kt++) {
            half8v af = load_wfrag(Wm, Hn, n0, 32 * kt + q * 8);   // k MUST include q*8
            const half8v* bf = (kt == 0) ? &hB.b0 : (kt == 1) ? &hB.b1 : (kt == 2) ? &hB.b2 : &hB.b3;
            acc = __builtin_amdgcn_mfma_f32_16x16x32_f16(af, *bf, acc, 0, 0, 0);
        }
        *(float4v*)(out + (size_t)mat * Bn * Hn + (size_t)(blk * 16 + m) * Hn + 16 * w + q * 4) = acc;
    }
}

extern "C" void kernel_launch(void* const* d_in, const int* in_sizes, int n_in,
                              void* d_out, int out_size, void* d_ws, size_t ws_size,
                              hipStream_t stream) {
    (void)in_sizes; (void)n_in; (void)d_ws; (void)ws_size; (void)out_size;
    odernn_kernel<<<dim3(Bn / 16), dim3(512), 0, stream>>>(
        (const float*)d_in[0],  (const float*)d_in[1],  (const float*)d_in[2],
        (const float*)d_in[3],  (const float*)d_in[4],  (const float*)d_in[5],
        (const float*)d_in[6],  (const float*)d_in[7],  (const float*)d_in[8],
        (const float*)d_in[9],  (const float*)d_in[10], (const float*)d_in[11],
        (const float*)d_in[12], (const float*)d_in[13], (float*)d_out);
}

// Round 8
// 756.985 us; speedup vs baseline: 2.7259x; 1.0046x over previous
//
#include <hip/hip_runtime.h>

#define Bn 4096
#define Tn 100
#define Dn 64
#define Hn 128

#define L2C  2.8853900817779268f   // 2*log2(e)
#define NL2E 1.4426950408889634f   // log2(e)

typedef _Float16 half8v __attribute__((ext_vector_type(8)));
typedef _Float16 half4v __attribute__((ext_vector_type(4)));
typedef __fp16   fp16x2 __attribute__((ext_vector_type(2)));   // cvt_pkrtz native type
typedef float    float4v __attribute__((ext_vector_type(4)));
typedef float    float2v __attribute__((ext_vector_type(2)));

// barrier: LDS-only drain (no vmcnt(0) -> x prefetch stays in flight)
#define BAR() asm volatile("s_waitcnt lgkmcnt(0)\ns_barrier" ::: "memory")

// tanh(u) where uL = u * 2*log2(e)  (L-scaled domain; scaling folded into weights)
__device__ __forceinline__ float tanhL(float uL) {
    return 1.0f - 2.0f * __builtin_amdgcn_rcpf(__builtin_amdgcn_exp2f(uL) + 1.0f);
}
// sigma(x) where sN = -x * log2(e)
__device__ __forceinline__ float sigN(float sN) {
    return __builtin_amdgcn_rcpf(1.0f + __builtin_amdgcn_exp2f(sN));
}
__device__ __forceinline__ float4v tanh4L(float4v uL) {
    float4v a;
#pragma unroll
    for (int r = 0; r < 4; r++) a[r] = tanhL(uL[r]);
    return a;
}
__device__ __forceinline__ half4v pack4(float4v v) {
    fp16x2 lo = __builtin_amdgcn_cvt_pkrtz(v[0], v[1]);   // v_cvt_pkrtz_f16_f32
    fp16x2 hi = __builtin_amdgcn_cvt_pkrtz(v[2], v[3]);
    struct P { fp16x2 a, b; } pp{lo, hi};
    return __builtin_bit_cast(half4v, pp);
}

// A-operand fragment of stationary weight W [n x ld], fp32 -> fp16, optional scale.
__device__ __forceinline__ half8v load_wfrag_s(const float* __restrict__ W, int ld, int n, int k, float s) {
    const float* p = W + (size_t)n * ld + k;
    float4v a = *(const float4v*)p * s;
    float4v b = *(const float4v*)(p + 4) * s;
    half8v r;
    r[0] = (_Float16)a[0]; r[1] = (_Float16)a[1]; r[2] = (_Float16)a[2]; r[3] = (_Float16)a[3];
    r[4] = (_Float16)b[0]; r[5] = (_Float16)b[1]; r[6] = (_Float16)b[2]; r[7] = (_Float16)b[3];
    return r;
}
__device__ __forceinline__ half8v load_wfrag(const float* __restrict__ W, int ld, int n, int k) {
    return load_wfrag_s(W, ld, n, k, 1.0f);
}

struct Bfrag { half8v b0, b1, b2, b3; };
struct Opair { float4v o1, o2; };

// Persistent ODE-RNN kernel. 256 blocks x 512 threads (8 waves, 2/SIMD).
// Round-8 changes (issue-diet continuation; structure = round 7):
//  * __launch_bounds__(512, 2): declares the occupancy we already run (2
//    waves/EU), raising per-wave arch-VGPR budget 128 -> 256. Hypothesis: the
//    default 128-arch split parks state/accumulators in AGPRs, paying
//    v_accvgpr_read/write on every VALU touch (~82 vs ~34 modeled inst per
//    interval). Budget 256 >= total live (~204) so no spill possible; occupancy
//    unchanged by construction. (Round 1's (512,4) CUT the budget to 64 — the
//    opposite direction.)
//  * c1q6 = 6*c1q as C-in of the u_h-update GEMM: s6L*(A M^T + 6 c1) ==
//    s6L*A M^T + subL*c1 (-4 fma per A-interval).
//  * dual-fma consumption of the two MFMA chains (u = u_h + c*o1 + c*o2):
//    same inst count, one less serial stage before tanh.
//  * pack+ds_write issued before the A-accumulation (write is on the
//    block-critical path; the accumulate is not).
__global__ __launch_bounds__(512, 2) void odernn_kernel(
    const float* __restrict__ x_seq, const float* __restrict__ t_seq,
    const float* __restrict__ W1,   const float* __restrict__ b1,
    const float* __restrict__ W2,   const float* __restrict__ b2,
    const float* __restrict__ W_ih, const float* __restrict__ W_hh,
    const float* __restrict__ b_ih, const float* __restrict__ b_hh,
    const float* __restrict__ W_mu, const float* __restrict__ b_mu,
    const float* __restrict__ W_lv, const float* __restrict__ b_lv,
    float* __restrict__ out)
{
    __shared__ _Float16 vbuf[2][16 * 136];   // h exchange, ping-pong across steps
    __shared__ _Float16 abuf[2][16 * 136];   // a_i / A exchange, ping-pong
    __shared__ _Float16 xbuf[16 * 72];       // x_t staging
    __shared__ float    ts_l[Tn];
    __shared__ float    c1s[Hn];             // c1 = b2 @ W1^T (RAW units)

    const int tid  = threadIdx.x;
    const int lane = tid & 63;
    const int w    = tid >> 6;        // wave 0..7 = n-tile owner
    const int q    = lane >> 4;
    const int m    = lane & 15;
    const int blk  = blockIdx.x;

    if (tid < Tn) ts_l[tid] = t_seq[tid];
    for (int i = tid; i < 16 * 136; i += 512) vbuf[0][i] = (_Float16)0.f;  // h0 = 0
    if (tid < Hn) {                                   // c1[n] = dot(b2, W1[n][:])
        float acc = 0.f;
        const float* r1 = W1 + (size_t)tid * Hn;
#pragma unroll 4
        for (int j = 0; j < Hn; j++) acc += b2[j] * r1[j];
        c1s[tid] = acc;
    }

    // ---- stationary weight fragments (register-resident, pre-scaled) ----
    const int n0 = 16 * w + m;
    half8v w1f[4], w2f[4], whhf[3][4], wihf[3][2];
#pragma unroll
    for (int kt = 0; kt < 4; kt++) {
        w1f[kt] = load_wfrag_s(W1, Hn, n0, 32 * kt + q * 8, L2C);   // L-scaled
        w2f[kt] = load_wfrag  (W2, Hn, n0, 32 * kt + q * 8);        // raw
    }
#pragma unroll
    for (int g = 0; g < 3; g++) {                 // 0=r, 1=z (x -log2e), 2=n (x L2C)
        float gs = (g == 2) ? L2C : -NL2E;
        int n = 128 * g + n0;
#pragma unroll
        for (int kt = 0; kt < 4; kt++) whhf[g][kt] = load_wfrag_s(W_hh, Hn, n, 32 * kt + q * 8, gs);
#pragma unroll
        for (int kt = 0; kt < 2; kt++) wihf[g][kt] = load_wfrag_s(W_ih, Dn, n, 32 * kt + q * 8, gs);
    }
    float4v b1q = *(const float4v*)(b1 + 16 * w + q * 4) * L2C;     // L-scaled
    float4v b2q = *(const float4v*)(b2 + 16 * w + q * 4);           // raw
    // r,z gate b_hh folded into gi C-in; all gate biases pre-scaled
    float4v bi0, bi1, bin, bhn;
    {
        float4v a, b;
        a = *(const float4v*)(b_ih + 0   + 16 * w + q * 4);
        b = *(const float4v*)(b_hh + 0   + 16 * w + q * 4);
        bi0 = (a + b) * (-NL2E);
        a = *(const float4v*)(b_ih + 128 + 16 * w + q * 4);
        b = *(const float4v*)(b_hh + 128 + 16 * w + q * 4);
        bi1 = (a + b) * (-NL2E);
        bin = *(const float4v*)(b_ih + 256 + 16 * w + q * 4) * L2C;
        bhn = *(const float4v*)(b_hh + 256 + 16 * w + q * 4) * L2C;
    }

    // ---- M = W1 @ W2 fragments (one-time fp32 dot; RAW — feeds raw g) ----
    float4v accM[4][2];
#pragma unroll
    for (int kt = 0; kt < 4; kt++) {
        float4v zz = {0.f, 0.f, 0.f, 0.f};
        accM[kt][0] = zz; accM[kt][1] = zz;
    }
    {
        const float* w1row = W1 + (size_t)n0 * Hn;
        for (int j = 0; j < Hn; j++) {
            float w1v = w1row[j];
            const float* w2r = W2 + (size_t)j * Hn + q * 8;
#pragma unroll
            for (int kt = 0; kt < 4; kt++) {
                float4v aa = *(const float4v*)(w2r + 32 * kt);
                float4v bb = *(const float4v*)(w2r + 32 * kt + 4);
                accM[kt][0] += w1v * aa;
                accM[kt][1] += w1v * bb;
            }
        }
    }
    half8v w21f[4];
#pragma unroll
    for (int kt = 0; kt < 4; kt++) {
#pragma unroll
        for (int r = 0; r < 4; r++) {
            w21f[kt][r]     = (_Float16)accM[kt][0][r];
            w21f[kt][r + 4] = (_Float16)accM[kt][1][r];
        }
    }

    float4v h = {0.f, 0.f, 0.f, 0.f};   // RAW units. C-layout: n = 16w+4q+r, col m

    // x prefetch: 2 floats/thread (512 thr x 2 = 16 rows x 64 cols)
    const int xrow = tid >> 5;
    const int xcol = (tid & 31) * 2;
    const float* xptr = x_seq + (size_t)(blk * 16 + xrow) * (Tn * Dn) + xcol;
    float2v xreg = *(const float2v*)xptr;

    // linear store/read slots
    const int wslot = m * 136 + 16 * w + 4 * q;     // C store
    const int rslot = m * 136 + q * 8;              // B-frag read base
    const int xws   = xrow * 72 + xcol;

    auto loadB = [&](const _Float16* base) -> Bfrag {
        const _Float16* p = base + rslot;
        Bfrag f;
        f.b0 = *(const half8v*)(p);
        f.b1 = *(const half8v*)(p + 32);
        f.b2 = *(const half8v*)(p + 64);
        f.b3 = *(const half8v*)(p + 96);
        return f;
    };
    // K=128 GEMM, 2 independent MFMA chains of 2; returns both partials so the
    // consumer can dual-fma (no o1+o2 serial add stage).
    auto mm4p = [&](const half8v* Wf, const Bfrag& B, float4v cin) -> Opair {
        Opair P;
        P.o1 = cin;
        P.o2 = (float4v){0.f, 0.f, 0.f, 0.f};
        P.o1 = __builtin_amdgcn_mfma_f32_16x16x32_f16(Wf[0], B.b0, P.o1, 0, 0, 0);
        P.o2 = __builtin_amdgcn_mfma_f32_16x16x32_f16(Wf[2], B.b2, P.o2, 0, 0, 0);
        P.o1 = __builtin_amdgcn_mfma_f32_16x16x32_f16(Wf[1], B.b1, P.o1, 0, 0, 0);
        P.o2 = __builtin_amdgcn_mfma_f32_16x16x32_f16(Wf[3], B.b3, P.o2, 0, 0, 0);
        return P;
    };
    auto mm4 = [&](const half8v* Wf, const Bfrag& B, float4v cin) -> float4v {
        Opair P = mm4p(Wf, B, cin);
        return P.o1 + P.o2;
    };

    _Float16* vc = vbuf[0];     // current h buffer
    _Float16* vn = vbuf[1];     // next-step h buffer

    float4v c1q, c1q6;          // RAW; c1q6 = 6*c1 (C-in of u_h-update GEMM)
    BAR();               // publish ts_l, c1s, vbuf[0](h0)
#pragma unroll
    for (int r = 0; r < 4; r++) c1q[r] = c1s[16 * w + q * 4 + r];
    c1q6 = c1q * 6.0f;
    const float4v zero4 = {0.f, 0.f, 0.f, 0.f};

#pragma unroll 1
    for (int t = 0; t < Tn; ++t) {
        // ---- stage x_t ----
        xbuf[xws]     = (_Float16)xreg[0];
        xbuf[xws + 1] = (_Float16)xreg[1];
        float tc   = ts_l[t];
        float tp   = (t > 0) ? ts_l[t - 1] : tc;
        float sub  = (tc - tp) * 0.25f;        // dt / N_RK4 (0 at t=0)
        float hsL  = sub * (0.5f * L2C);       // L-scaled coefficients
        float subL = sub * L2C;
        float s6L  = sub * (L2C / 6.0f);
        float s6   = sub * (1.0f / 6.0f);      // raw (h update)
        BAR();                                 // publish xbuf + vc(h)
        if (t + 1 < Tn) xreg = *(const float2v*)(xptr + (t + 1) * Dn);

        // ---- u_h = L*(h W1^T + b1) via pre-scaled fragments ----
        float4v u_h = mm4(w1f, loadB(vc), b1q);

        if (sub != 0.0f) {
            float4v Abar = zero4;
#pragma unroll 1
            for (int s = 0; s < 4; s++) {
                float4v a1 = tanh4L(u_h);
                *(half4v*)(abuf[0] + wslot) = pack4(a1);    // write first
                float4v A  = a1;
                BAR();
                {
                    Opair P = mm4p(w21f, loadB(abuf[0]), c1q);   // a1 M^T + c1 (raw)
                    float4v u = u_h + hsL * P.o1 + hsL * P.o2;
                    float4v a2 = tanh4L(u);
                    *(half4v*)(abuf[1] + wslot) = pack4(a2);     // write before accum
                    A += 2.0f * a2;
                }
                BAR();
                {
                    Opair P = mm4p(w21f, loadB(abuf[1]), c1q);
                    float4v u = u_h + hsL * P.o1 + hsL * P.o2;
                    float4v a3 = tanh4L(u);
                    *(half4v*)(abuf[0] + wslot) = pack4(a3);
                    A += 2.0f * a3;
                }
                BAR();
                {
                    Opair P = mm4p(w21f, loadB(abuf[0]), c1q);
                    float4v u = u_h + subL * P.o1 + subL * P.o2;
                    float4v a4 = tanh4L(u);
                    A += a4;
                    Abar += A;
                    if (s < 3) {             // s=3: A M^T only fed the dead u_h update — skip
                        *(half4v*)(abuf[1] + wslot) = pack4(A);  // |A| <= 6, fp16 ok
                    }
                }
                if (s < 3) {
                    BAR();
                    // u_h += s6L*(A M^T + 6 c1)  ==  s6L*A M^T + subL*c1
                    Opair P = mm4p(w21f, loadB(abuf[1]), c1q6);
                    u_h += s6L * P.o1 + s6L * P.o2;
                }
            }
            // deferred h update: one W2-GEMM per step (raw units)
            *(half4v*)(abuf[1] + wslot) = pack4(Abar);          // |Abar| <= 24, fp16 ok
            BAR();
            {
                Opair P = mm4p(w2f, loadB(abuf[1]), zero4);
                h += s6 * P.o1 + s6 * P.o2 + (4.0f * sub) * b2q;
            }
            *(half4v*)(vc + wslot) = pack4(h);                  // publish post-RK h
            BAR();
        }
        // (sub==0: vc already holds h)

        // ---- gi = x Wih^T + biases  and  gh = h Whh^T (merged, pre-scaled) ----
        float4v gi[3], gh[3];
        {
            half8v xf0 = *(const half8v*)(xbuf + m * 72 + q * 8);
            half8v xf1 = *(const half8v*)(xbuf + m * 72 + q * 8 + 32);
            Bfrag hB = loadB(vc);
#pragma unroll
            for (int g = 0; g < 3; g++) {
                float4v acc = (g == 0) ? bi0 : (g == 1) ? bi1 : bin;
                acc = __builtin_amdgcn_mfma_f32_16x16x32_f16(wihf[g][0], xf0, acc, 0, 0, 0);
                acc = __builtin_amdgcn_mfma_f32_16x16x32_f16(wihf[g][1], xf1, acc, 0, 0, 0);
                gi[g] = acc;
                float4v a2c = (g == 2) ? bhn : zero4;
                a2c = __builtin_amdgcn_mfma_f32_16x16x32_f16(whhf[g][0], hB.b0, a2c, 0, 0, 0);
                a2c = __builtin_amdgcn_mfma_f32_16x16x32_f16(whhf[g][1], hB.b1, a2c, 0, 0, 0);
                a2c = __builtin_amdgcn_mfma_f32_16x16x32_f16(whhf[g][2], hB.b2, a2c, 0, 0, 0);
                a2c = __builtin_amdgcn_mfma_f32_16x16x32_f16(whhf[g][3], hB.b3, a2c, 0, 0, 0);
                gh[g] = a2c;
            }
        }
        // no barrier: GRU writes the OTHER vbuf (ping-pong removes WAR hazard)

        // ---- GRU (registers; gates in scaled domains) ----
        {
            float4v hv;
#pragma unroll
            for (int r = 0; r < 4; r++) {
                float rr = sigN(gi[0][r] + gh[0][r]);           // pre-scaled by -log2e
                float zz = sigN(gi[1][r] + gh[1][r]);
                float nn = tanhL(gi[2][r] + rr * gh[2][r]);     // pre-scaled by L2C
                hv[r] = nn + zz * (h[r] - nn);
            }
            h = hv;
            *(half4v*)(vn + wslot) = pack4(hv);
        }
        // swap buffers; loop-top barrier publishes vn as the new vc
        _Float16* tmp = vc; vc = vn; vn = tmp;
    }

    BAR();

    // ---- epilogue: mu / logvar (vc holds final h after last swap; raw) ----
#pragma unroll
    for (int mat = 0; mat < 2; mat++) {
        const float* Wm = mat ? W_lv : W_mu;
        const float* bm = mat ? b_lv : b_mu;
        float4v acc = *(const float4v*)(bm + 16 * w + q * 4);
        Bfrag hB = loadB(vc);
#pragma unroll
        for (int kt = 0; kt < 4; kt++) {
            half8v af = load_wfrag(Wm, Hn, n0, 32 * kt + q * 8);   // k MUST include q*8
            const half8v* bf = (kt == 0) ? &hB.b0 : (kt == 1) ? &hB.b1 : (kt == 2) ? &hB.b2 : &hB.b3;
            acc = __builtin_amdgcn_mfma_f32_16x16x32_f16(af, *bf, acc, 0, 0, 0);
        }
        *(float4v*)(out + (size_t)mat * Bn * Hn + (size_t)(blk * 16 + m) * Hn + 16 * w + q * 4) = acc;
    }
}

extern "C" void kernel_launch(void* const* d_in, const int* in_sizes, int n_in,
                              void* d_out, int out_size, void* d_ws, size_t ws_size,
                              hipStream_t stream) {
    (void)in_sizes; (void)n_in; (void)d_ws; (void)ws_size; (void)out_size;
    odernn_kernel<<<dim3(Bn / 16), dim3(512), 0, stream>>>(
        (const float*)d_in[0],  (const float*)d_in[1],  (const float*)d_in[2],
        (const float*)d_in[3],  (const float*)d_in[4],  (const float*)d_in[5],
        (const float*)d_in[6],  (const float*)d_in[7],  (const float*)d_in[8],
        (const float*)d_in[9],  (const float*)d_in[10], (const float*)d_in[11],
        (const float*)d_in[12], (const float*)d_in[13], (float*)d_out);
}